// Round 1
// baseline (1795.920 us; speedup 1.0000x reference)
//
#include <hip/hip_runtime.h>

#define MEM_N 262144
#define DIM 256
#define NBATCH 256
#define TCAP 4096

typedef __attribute__((ext_vector_type(8))) short short8;
typedef __attribute__((ext_vector_type(4))) float f32x4;

__device__ __forceinline__ unsigned short bf16_rne(float f) {
  unsigned u = __builtin_bit_cast(unsigned, f);
  u += 0x7FFFu + ((u >> 16) & 1u);
  return (unsigned short)(u >> 16);
}
__device__ __forceinline__ float bf16_f32(unsigned short h) {
  unsigned u = ((unsigned)h) << 16;
  return __builtin_bit_cast(float, u);
}
__device__ __forceinline__ unsigned flip32(float f) {
  unsigned u = __builtin_bit_cast(unsigned, f);
  return u ^ ((unsigned)((int)u >> 31) | 0x80000000u);
}
__device__ __forceinline__ float unflip32(unsigned k) {
  unsigned u = (k & 0x80000000u) ? (k ^ 0x80000000u) : ~k;
  return __builtin_bit_cast(float, u);
}

// ---------------- query = normalize(x @ W^T + b) ----------------
__global__ __launch_bounds__(256) void k_query(
    const float* __restrict__ x, const float* __restrict__ W,
    const float* __restrict__ b, float* __restrict__ q,
    unsigned short* __restrict__ qhi, unsigned short* __restrict__ qlo) {
  __shared__ float Wt[256][33];
  __shared__ float xs[256];
  __shared__ float red[256];
  const int r = blockIdx.x, t = threadIdx.x;
  xs[t] = x[r * DIM + t];
  float acc = b[t];
  for (int k0 = 0; k0 < DIM; k0 += 32) {
    __syncthreads();
    for (int i = 0; i < 32; i++) {
      int e = i * 256 + t;
      int j = e >> 5, c = e & 31;
      Wt[j][c] = W[j * DIM + k0 + c];
    }
    __syncthreads();
#pragma unroll
    for (int c = 0; c < 32; c++) acc += xs[k0 + c] * Wt[t][c];
  }
  red[t] = acc * acc;
  __syncthreads();
  for (int s = 128; s > 0; s >>= 1) {
    if (t < s) red[t] += red[t + s];
    __syncthreads();
  }
  float nrm = fmaxf(sqrtf(red[0]), 1e-12f);
  float qv = acc / nrm;
  q[r * DIM + t] = qv;
  unsigned short h = bf16_rne(qv);
  qhi[r * DIM + t] = h;
  qlo[r * DIM + t] = bf16_rne(qv - bf16_f32(h));
}

// ---------------- scores = query @ keys^T (split-bf16, 3-term MFMA) ----------------
__global__ __launch_bounds__(256) void k_gemm(
    const unsigned short* __restrict__ qhi, const unsigned short* __restrict__ qlo,
    const float* __restrict__ keys, float* __restrict__ scores) {
  __shared__ unsigned short Ah[256][40];
  __shared__ unsigned short Al[256][40];
  __shared__ unsigned short Bh[64][40];
  __shared__ unsigned short Bl[64][40];
  const int t = threadIdx.x;
  const int slot0 = blockIdx.x * 64;
  const int w = t >> 6, l = t & 63;
  const int lrow = l & 15, lk = (l >> 4) * 8;
  const int rb = t >> 2, ks = (t & 3) * 8;

  f32x4 acc[4][4];
#pragma unroll
  for (int i = 0; i < 4; ++i)
#pragma unroll
    for (int j = 0; j < 4; ++j) acc[i][j] = f32x4{0.f, 0.f, 0.f, 0.f};

  for (int k0 = 0; k0 < DIM; k0 += 32) {
    // stage A (pre-split bf16 hi/lo): thread t -> row t, 32 elems
    {
      const uint4* gh = (const uint4*)(qhi + t * DIM + k0);
      const uint4* gl = (const uint4*)(qlo + t * DIM + k0);
      uint4* sh = (uint4*)(&Ah[t][0]);
      uint4* sl = (uint4*)(&Al[t][0]);
#pragma unroll
      for (int s = 0; s < 4; s++) { sh[s] = gh[s]; sl[s] = gl[s]; }
    }
    // stage B: load fp32 keys, split to hi/lo bf16
    {
      const float4* g = (const float4*)(keys + (size_t)(slot0 + rb) * DIM + k0 + ks);
      float4 v0 = g[0], v1 = g[1];
      float vv[8] = {v0.x, v0.y, v0.z, v0.w, v1.x, v1.y, v1.z, v1.w};
      unsigned hp[4], lp[4];
#pragma unroll
      for (int i = 0; i < 4; i++) {
        unsigned short h0 = bf16_rne(vv[2 * i]), h1 = bf16_rne(vv[2 * i + 1]);
        unsigned short l0 = bf16_rne(vv[2 * i] - bf16_f32(h0));
        unsigned short l1 = bf16_rne(vv[2 * i + 1] - bf16_f32(h1));
        hp[i] = (unsigned)h0 | ((unsigned)h1 << 16);
        lp[i] = (unsigned)l0 | ((unsigned)l1 << 16);
      }
      uint4 th, tl;
      th.x = hp[0]; th.y = hp[1]; th.z = hp[2]; th.w = hp[3];
      tl.x = lp[0]; tl.y = lp[1]; tl.z = lp[2]; tl.w = lp[3];
      *(uint4*)(&Bh[rb][ks]) = th;
      *(uint4*)(&Bl[rb][ks]) = tl;
    }
    __syncthreads();
    short8 ah[4], al[4], bh[4], bl[4];
#pragma unroll
    for (int mf = 0; mf < 4; mf++) {
      int row = w * 64 + mf * 16 + lrow;
      ah[mf] = *(const short8*)(&Ah[row][lk]);
      al[mf] = *(const short8*)(&Al[row][lk]);
    }
#pragma unroll
    for (int nf = 0; nf < 4; nf++) {
      int row = nf * 16 + lrow;
      bh[nf] = *(const short8*)(&Bh[row][lk]);
      bl[nf] = *(const short8*)(&Bl[row][lk]);
    }
#pragma unroll
    for (int mf = 0; mf < 4; mf++)
#pragma unroll
      for (int nf = 0; nf < 4; nf++) {
        acc[mf][nf] = __builtin_amdgcn_mfma_f32_16x16x32_bf16(al[mf], bh[nf], acc[mf][nf], 0, 0, 0);
        acc[mf][nf] = __builtin_amdgcn_mfma_f32_16x16x32_bf16(ah[mf], bl[nf], acc[mf][nf], 0, 0, 0);
        acc[mf][nf] = __builtin_amdgcn_mfma_f32_16x16x32_bf16(ah[mf], bh[nf], acc[mf][nf], 0, 0, 0);
      }
    __syncthreads();
  }
  const int orow = (l >> 4) * 4;
  const int ocol = l & 15;
#pragma unroll
  for (int mf = 0; mf < 4; mf++)
#pragma unroll
    for (int nf = 0; nf < 4; nf++) {
      size_t base = (size_t)(w * 64 + mf * 16 + orow) * MEM_N + slot0 + nf * 16 + ocol;
#pragma unroll
      for (int j = 0; j < 4; j++) scores[base + (size_t)j * MEM_N] = acc[mf][nf][j];
    }
}

// ---------------- exact streaming top-256 machinery ----------------
__device__ void bitonic_desc(unsigned long long* a, int N, int t) {
  for (int k = 2; k <= N; k <<= 1) {
    for (int j = k >> 1; j > 0; j >>= 1) {
      for (int i = t; i < N; i += 256) {
        int p = i ^ j;
        if (p > i) {
          unsigned long long xv = a[i], yv = a[p];
          bool up = ((i & k) == 0);
          if (up ? (xv < yv) : (xv > yv)) { a[i] = yv; a[p] = xv; }
        }
      }
      __syncthreads();
    }
  }
}

__device__ void trim256(unsigned long long* cand, int* cnt,
                        unsigned long long* cutoff, int t) {
  int n = *cnt;
  for (int i = t; i < TCAP; i += 256)
    if (i >= n) cand[i] = 0ULL;
  __syncthreads();
  bitonic_desc(cand, TCAP, t);
  if (t == 0) { *cnt = 256; *cutoff = cand[255]; }
}

template <typename F>
__device__ void top256_stream(F getv, int idx_base, int total,
                              unsigned long long* cand, int* cnt,
                              unsigned long long* cutoff, int t) {
  if (t == 0) { *cnt = 0; *cutoff = 0ULL; }
  __syncthreads();
  for (int base = 0; base < total; base += 2048) {
    unsigned long long cut = *cutoff;
    float v[8];
#pragma unroll
    for (int u = 0; u < 8; u++) v[u] = getv(idx_base + base + u * 256 + t);
#pragma unroll
    for (int u = 0; u < 8; u++) {
      int gi = idx_base + base + u * 256 + t;
      unsigned long long key =
          (((unsigned long long)flip32(v[u])) << 32) | (unsigned)(~(unsigned)gi);
      if (key > cut) {
        int p = atomicAdd(cnt, 1);
        if (p < TCAP) cand[p] = key;
      }
    }
    __syncthreads();
    if (*cnt > 2048) trim256(cand, cnt, cutoff, t);
    __syncthreads();
  }
  trim256(cand, cnt, cutoff, t);
  __syncthreads();
}

// ---------------- per-row top-k + softmax + loss + yhat ----------------
__global__ __launch_bounds__(256) void k_topk(
    const float* __restrict__ scores, const int* __restrict__ values,
    const int* __restrict__ yv, float* __restrict__ out,
    float* __restrict__ loss_arr, int* __restrict__ corr, int* __restrict__ yidx) {
  __shared__ unsigned long long cand[TCAP];
  __shared__ int cnt;
  __shared__ unsigned long long cutoff;
  __shared__ float red[256];
  const int r = blockIdx.x, t = threadIdx.x;
  const float* row = scores + (size_t)r * MEM_N;
  auto getv = [row](int g) { return row[g]; };
  top256_stream(getv, 0, MEM_N, cand, &cnt, &cutoff, t);

  unsigned long long mykey = cand[t];
  int midx = (int)(~(unsigned)(mykey & 0xFFFFFFFFull));
  float msc = unflip32((unsigned)(mykey >> 32));
  int yr = yv[r];
  float mask = (values[midx] == yr) ? 1.0f : 0.0f;
  float mtop = unflip32((unsigned)(cand[0] >> 32));

  // softmax (TEMP = 1.0)
  float e = expf(msc - mtop);
  red[t] = e; __syncthreads();
  for (int s = 128; s > 0; s >>= 1) { if (t < s) red[t] += red[t + s]; __syncthreads(); }
  float denom = red[0]; __syncthreads();
  out[256 + r * 256 + t] = e / denom;

  red[t] = msc * mask; __syncthreads();
  for (int s = 128; s > 0; s >>= 1) { if (t < s) red[t] = fmaxf(red[t], red[t + s]); __syncthreads(); }
  float posr = red[0]; __syncthreads();

  red[t] = msc * (1.0f - mask); __syncthreads();
  for (int s = 128; s > 0; s >>= 1) { if (t < s) red[t] = fmaxf(red[t], red[t + s]); __syncthreads(); }
  float negr = red[0]; __syncthreads();

  red[t] = mask; __syncthreads();
  for (int s = 128; s > 0; s >>= 1) { if (t < s) red[t] += red[t + s]; __syncthreads(); }
  float hp = (red[0] > 0.0f) ? 1.0f : 0.0f;

  if (t == 0) {
    float pos = posr * hp;
    loss_arr[r] = fmaxf(negr - pos + 0.1f, 0.0f);
    int i0 = (int)(~(unsigned)(cand[0] & 0xFFFFFFFFull));
    out[r] = (float)values[i0];         // y_hat as float
    yidx[r] = i0;
    corr[r] = (values[i0] == yr) ? 1 : 0;
  }
}

// ---------------- age/values init ----------------
__global__ __launch_bounds__(256) void k_age(
    const float* __restrict__ age, const int* __restrict__ values,
    float* __restrict__ age_out, float* __restrict__ vals_out) {
  int i = blockIdx.x * 256 + threadIdx.x;
  age_out[i] = age[i] + 1.0f;
  vals_out[i] = (float)values[i];
}

__global__ void k_reset(const int* __restrict__ corr, const int* __restrict__ yidx,
                        float* __restrict__ age_out) {
  int t = threadIdx.x;
  if (corr[t]) age_out[yidx[t]] = 0.0f;
}

// ---------------- oldest = top-256 of age_noisy ----------------
__global__ __launch_bounds__(256) void k_oldA(
    const float* __restrict__ age_out, const float* __restrict__ un,
    unsigned long long* __restrict__ cand_g) {
  __shared__ unsigned long long cand[TCAP];
  __shared__ int cnt;
  __shared__ unsigned long long cutoff;
  const int t = threadIdx.x;
  const int base = blockIdx.x * 16384;
  auto getv = [age_out, un](int g) {
    return age_out[g] + (2.0f * un[g] - 1.0f) * 8.0f;
  };
  top256_stream(getv, base, 16384, cand, &cnt, &cutoff, t);
  cand_g[blockIdx.x * 256 + t] = cand[t];
}

__global__ __launch_bounds__(256) void k_oldB(
    const unsigned long long* __restrict__ cand_g, const int* __restrict__ corr,
    const float* __restrict__ loss_arr, int* __restrict__ dest,
    float* __restrict__ out_loss) {
  __shared__ unsigned long long cand[4096];
  __shared__ int olds[256];
  __shared__ int pre[256];
  __shared__ float red[256];
  const int t = threadIdx.x;
  for (int i = t; i < 4096; i += 256) cand[i] = cand_g[i];
  __syncthreads();
  bitonic_desc(cand, 4096, t);
  olds[t] = (int)(~(unsigned)(cand[t] & 0xFFFFFFFFull));
  int inc = corr[t] ? 0 : 1;
  pre[t] = inc;
  __syncthreads();
  for (int off = 1; off < 256; off <<= 1) {
    int v = (t >= off) ? pre[t - off] : 0;
    __syncthreads();
    pre[t] += v;
    __syncthreads();
  }
  int rank = pre[t] - 1;
  dest[t] = inc ? olds[rank] : -1;
  red[t] = loss_arr[t]; __syncthreads();
  for (int s = 128; s > 0; s >>= 1) { if (t < s) red[t] += red[t + s]; __syncthreads(); }
  if (t == 0) *out_loss = red[0] * (1.0f / 256.0f);
}

// ---------------- keys copy + scatter updates ----------------
__global__ __launch_bounds__(256) void k_copy(const float* __restrict__ in,
                                              float* __restrict__ outp) {
  size_t i = (size_t)blockIdx.x * 256 + threadIdx.x;
  size_t stride = (size_t)gridDim.x * 256;
  for (; i < (size_t)MEM_N * DIM; i += stride) outp[i] = in[i];
}

__global__ __launch_bounds__(256) void k_correct(
    const int* __restrict__ corr, const int* __restrict__ yidx,
    const float* __restrict__ keys, const float* __restrict__ q,
    float* __restrict__ keys_out) {
  const int r = blockIdx.x;
  if (!corr[r]) return;
  const int t = threadIdx.x;
  __shared__ float red[256];
  int d = yidx[r];
  float v = keys[(size_t)d * DIM + t] + q[r * DIM + t];
  red[t] = v * v; __syncthreads();
  for (int s = 128; s > 0; s >>= 1) { if (t < s) red[t] += red[t + s]; __syncthreads(); }
  float nrm = fmaxf(sqrtf(red[0]), 1e-12f);
  keys_out[(size_t)d * DIM + t] = v / nrm;
}

__global__ __launch_bounds__(256) void k_incorrect(
    const int* __restrict__ dest, const float* __restrict__ q,
    const int* __restrict__ yv, float* __restrict__ keys_out,
    float* __restrict__ vals_out, float* __restrict__ age_out) {
  const int r = blockIdx.x;
  int d = dest[r];
  if (d < 0) return;
  const int t = threadIdx.x;
  keys_out[(size_t)d * DIM + t] = q[r * DIM + t];
  if (t == 0) {
    vals_out[d] = (float)yv[r];
    age_out[d] = 0.0f;
  }
}

extern "C" void kernel_launch(void* const* d_in, const int* in_sizes, int n_in,
                              void* d_out, int out_size, void* d_ws, size_t ws_size,
                              hipStream_t stream) {
  const float* x = (const float*)d_in[0];
  const int* y = (const int*)d_in[1];
  const float* W = (const float*)d_in[2];
  const float* b = (const float*)d_in[3];
  const float* keys = (const float*)d_in[4];
  const int* values = (const int*)d_in[5];
  const float* age = (const float*)d_in[6];
  const float* un = (const float*)d_in[7];
  float* out = (float*)d_out;

  char* ws = (char*)d_ws;
  float* q = (float*)ws;                                     // 256 KB
  unsigned short* qhi = (unsigned short*)(ws + 262144);      // 128 KB
  unsigned short* qlo = (unsigned short*)(ws + 393216);      // 128 KB
  float* loss_arr = (float*)(ws + 524288);                   // 1 KB
  int* corr = (int*)(ws + 525312);                           // 1 KB
  int* yidx = (int*)(ws + 526336);                           // 1 KB
  unsigned long long* cand_g = (unsigned long long*)(ws + 527360);  // 32 KB
  int* dest = (int*)(ws + 560128);                           // 1 KB

  // d_out layout (floats): yhat[256] | softmax[65536] | loss[1] | keys[67108864]
  //                        | values[262144] | age[262144]
  const size_t LOSS_OFF = 65792, KEYS_OFF = 65793, VALS_OFF = 67174657,
               AGE_OFF = 67436801;
  float* scores = out + 65796;  // 16B-aligned scratch inside keys region (+3 spill
                                // into values region, rewritten later by k_age)
  float* keys_out = out + KEYS_OFF;
  float* vals_out = out + VALS_OFF;
  float* age_out = out + AGE_OFF;

  k_query<<<dim3(256), dim3(256), 0, stream>>>(x, W, b, q, qhi, qlo);
  k_gemm<<<dim3(4096), dim3(256), 0, stream>>>(qhi, qlo, keys, scores);
  k_topk<<<dim3(256), dim3(256), 0, stream>>>(scores, values, y, out, loss_arr, corr, yidx);
  k_age<<<dim3(1024), dim3(256), 0, stream>>>(age, values, age_out, vals_out);
  k_reset<<<dim3(1), dim3(256), 0, stream>>>(corr, yidx, age_out);
  k_oldA<<<dim3(16), dim3(256), 0, stream>>>(age_out, un, cand_g);
  k_oldB<<<dim3(1), dim3(256), 0, stream>>>(cand_g, corr, loss_arr, dest, out + LOSS_OFF);
  k_copy<<<dim3(4096), dim3(256), 0, stream>>>(keys, keys_out);
  k_correct<<<dim3(256), dim3(256), 0, stream>>>(corr, yidx, keys, q, keys_out);
  k_incorrect<<<dim3(256), dim3(256), 0, stream>>>(dest, q, y, keys_out, vals_out, age_out);
}

// Round 2
// 1113.063 us; speedup vs baseline: 1.6135x; 1.6135x over previous
//
#include <hip/hip_runtime.h>

#define MEM_N 262144
#define DIM 256
#define NBATCH 256
#define TCAP 4096
#define NSEG 8
#define SEG_SZ 32768

typedef __attribute__((ext_vector_type(8))) short short8;
typedef __attribute__((ext_vector_type(4))) float f32x4;

__device__ __forceinline__ unsigned short bf16_rne(float f) {
  unsigned u = __builtin_bit_cast(unsigned, f);
  u += 0x7FFFu + ((u >> 16) & 1u);
  return (unsigned short)(u >> 16);
}
__device__ __forceinline__ float bf16_f32(unsigned short h) {
  unsigned u = ((unsigned)h) << 16;
  return __builtin_bit_cast(float, u);
}
__device__ __forceinline__ unsigned flip32(float f) {
  unsigned u = __builtin_bit_cast(unsigned, f);
  return u ^ ((unsigned)((int)u >> 31) | 0x80000000u);
}
__device__ __forceinline__ float unflip32(unsigned k) {
  unsigned u = (k & 0x80000000u) ? (k ^ 0x80000000u) : ~k;
  return __builtin_bit_cast(float, u);
}

// ---------------- query = normalize(x @ W^T + b) ----------------
__global__ __launch_bounds__(256) void k_query(
    const float* __restrict__ x, const float* __restrict__ W,
    const float* __restrict__ b, float* __restrict__ q,
    unsigned short* __restrict__ qhi, unsigned short* __restrict__ qlo) {
  __shared__ float Wt[256][36];
  __shared__ float xs[256];
  __shared__ float red[256];
  const int r = blockIdx.x, t = threadIdx.x;
  xs[t] = x[r * DIM + t];
  float acc = b[t];
  for (int k0 = 0; k0 < DIM; k0 += 32) {
    __syncthreads();
#pragma unroll
    for (int i = 0; i < 8; i++) {
      int f = i * 256 + t;
      int j = f >> 3, c = (f & 7) * 4;
      *(float4*)&Wt[j][c] = *(const float4*)&W[j * DIM + k0 + c];
    }
    __syncthreads();
#pragma unroll
    for (int c = 0; c < 32; c++) acc = fmaf(xs[k0 + c], Wt[t][c], acc);
  }
  red[t] = acc * acc;
  __syncthreads();
  for (int s = 128; s > 0; s >>= 1) {
    if (t < s) red[t] += red[t + s];
    __syncthreads();
  }
  float nrm = fmaxf(sqrtf(red[0]), 1e-12f);
  float qv = acc / nrm;
  q[r * DIM + t] = qv;
  unsigned short h = bf16_rne(qv);
  qhi[r * DIM + t] = h;
  qlo[r * DIM + t] = bf16_rne(qv - bf16_f32(h));
}

// ---------------- scores = query @ keys^T (split-bf16, 3-term MFMA) ----------------
__global__ __launch_bounds__(256) void k_gemm(
    const unsigned short* __restrict__ qhi, const unsigned short* __restrict__ qlo,
    const float* __restrict__ keys, float* __restrict__ scores) {
  __shared__ unsigned short Ah[256][40];
  __shared__ unsigned short Al[256][40];
  __shared__ unsigned short Bh[64][40];
  __shared__ unsigned short Bl[64][40];
  const int t = threadIdx.x;
  const int slot0 = blockIdx.x * 64;
  const int w = t >> 6, l = t & 63;
  const int lrow = l & 15, lk = (l >> 4) * 8;

  f32x4 acc[4][4];
#pragma unroll
  for (int i = 0; i < 4; ++i)
#pragma unroll
    for (int j = 0; j < 4; ++j) acc[i][j] = f32x4{0.f, 0.f, 0.f, 0.f};

  for (int k0 = 0; k0 < DIM; k0 += 32) {
    // stage A (pre-split bf16 hi/lo), coalesced uint4
#pragma unroll
    for (int i = 0; i < 4; i++) {
      int f = i * 256 + t;  // [0,1024)
      int row = f >> 2, s = f & 3;
      *(uint4*)&Ah[row][s * 8] = *(const uint4*)(qhi + row * DIM + k0 + s * 8);
      *(uint4*)&Al[row][s * 8] = *(const uint4*)(qlo + row * DIM + k0 + s * 8);
    }
    // stage B: coalesced float4 keys, split to hi/lo bf16
#pragma unroll
    for (int i = 0; i < 2; i++) {
      int f = i * 256 + t;  // [0,512)
      int row = f >> 3, c = f & 7;
      float4 v = *(const float4*)(keys + (size_t)(slot0 + row) * DIM + k0 + c * 4);
      unsigned short h0 = bf16_rne(v.x), h1 = bf16_rne(v.y), h2 = bf16_rne(v.z), h3 = bf16_rne(v.w);
      unsigned short g0 = bf16_rne(v.x - bf16_f32(h0)), g1 = bf16_rne(v.y - bf16_f32(h1));
      unsigned short g2 = bf16_rne(v.z - bf16_f32(h2)), g3 = bf16_rne(v.w - bf16_f32(h3));
      uint2 hp, lp;
      hp.x = (unsigned)h0 | ((unsigned)h1 << 16);
      hp.y = (unsigned)h2 | ((unsigned)h3 << 16);
      lp.x = (unsigned)g0 | ((unsigned)g1 << 16);
      lp.y = (unsigned)g2 | ((unsigned)g3 << 16);
      *(uint2*)&Bh[row][c * 4] = hp;
      *(uint2*)&Bl[row][c * 4] = lp;
    }
    __syncthreads();
    short8 ah[4], al[4], bh[4], bl[4];
#pragma unroll
    for (int mf = 0; mf < 4; mf++) {
      int row = w * 64 + mf * 16 + lrow;
      ah[mf] = *(const short8*)(&Ah[row][lk]);
      al[mf] = *(const short8*)(&Al[row][lk]);
    }
#pragma unroll
    for (int nf = 0; nf < 4; nf++) {
      int row = nf * 16 + lrow;
      bh[nf] = *(const short8*)(&Bh[row][lk]);
      bl[nf] = *(const short8*)(&Bl[row][lk]);
    }
#pragma unroll
    for (int mf = 0; mf < 4; mf++)
#pragma unroll
      for (int nf = 0; nf < 4; nf++) {
        acc[mf][nf] = __builtin_amdgcn_mfma_f32_16x16x32_bf16(al[mf], bh[nf], acc[mf][nf], 0, 0, 0);
        acc[mf][nf] = __builtin_amdgcn_mfma_f32_16x16x32_bf16(ah[mf], bl[nf], acc[mf][nf], 0, 0, 0);
        acc[mf][nf] = __builtin_amdgcn_mfma_f32_16x16x32_bf16(ah[mf], bh[nf], acc[mf][nf], 0, 0, 0);
      }
    __syncthreads();
  }
  // epilogue: LDS transpose (reuse Ah region) -> 16B/lane coalesced stores
  float* tr2 = ((float*)&Ah[0][0]) + w * (16 * 68);
#pragma unroll
  for (int mf = 0; mf < 4; mf++) {
#pragma unroll
    for (int nf = 0; nf < 4; nf++)
#pragma unroll
      for (int j = 0; j < 4; j++)
        tr2[((l >> 4) * 4 + j) * 68 + nf * 16 + (l & 15)] = acc[mf][nf][j];
#pragma unroll
    for (int it = 0; it < 4; it++) {
      float4 vv = *(float4*)&tr2[(it * 4 + (l >> 4)) * 68 + 4 * (l & 15)];
      size_t row = (size_t)(w * 64 + mf * 16 + it * 4 + (l >> 4));
      *(float4*)&scores[row * MEM_N + slot0 + 4 * (l & 15)] = vv;
    }
  }
}

// ---------------- sort helpers ----------------
__device__ void bitonic_desc(unsigned long long* a, int N, int t) {
  for (int k = 2; k <= N; k <<= 1) {
    for (int j = k >> 1; j > 0; j >>= 1) {
      for (int i = t; i < N; i += 256) {
        int p = i ^ j;
        if (p > i) {
          unsigned long long xv = a[i], yv = a[p];
          bool up = ((i & k) == 0);
          if (up ? (xv < yv) : (xv > yv)) { a[i] = yv; a[p] = xv; }
        }
      }
      __syncthreads();
    }
  }
}

__device__ void trim256(unsigned long long* cand, int* cnt,
                        unsigned long long* cutoff, int t) {
  int n = *cnt;
  for (int i = t; i < TCAP; i += 256)
    if (i >= n) cand[i] = 0ULL;
  __syncthreads();
  bitonic_desc(cand, TCAP, t);
  if (t == 0) { *cnt = 256; *cutoff = cand[255]; }
}

// ---------------- top-k stage 1: per-(row,segment) exact top-256 ----------------
__global__ __launch_bounds__(256) void k_topk1(
    const float* __restrict__ scores, unsigned long long* __restrict__ cand_g) {
  __shared__ unsigned long long cand[TCAP];
  __shared__ int cnt;
  __shared__ unsigned long long cutoff;
  __shared__ unsigned long long redu[256];
  const int seg = blockIdx.x, r = blockIdx.y, t = threadIdx.x;
  const float* p = scores + (size_t)r * MEM_N + (size_t)seg * SEG_SZ;
  // pass 1: min over per-thread maxima => provable lower bound on 256th-largest
  unsigned long long mk = 0ULL;
  for (int u = 0; u < 32; u++) {
    float4 v = *(const float4*)(p + u * 1024 + t * 4);
    int c0 = seg * SEG_SZ + u * 1024 + t * 4;
    float vv[4] = {v.x, v.y, v.z, v.w};
#pragma unroll
    for (int e = 0; e < 4; e++) {
      unsigned long long k =
          (((unsigned long long)flip32(vv[e])) << 32) | (unsigned)(~(unsigned)(c0 + e));
      mk = k > mk ? k : mk;
    }
  }
  redu[t] = mk;
  __syncthreads();
  for (int s = 128; s > 0; s >>= 1) {
    if (t < s) redu[t] = (redu[t] < redu[t + s]) ? redu[t] : redu[t + s];
    __syncthreads();
  }
  if (t == 0) { cnt = 0; cutoff = redu[0] - 1ULL; }
  __syncthreads();
  // pass 2: filtered insert (L2-hot re-read)
  for (int base = 0; base < SEG_SZ; base += 2048) {
    unsigned long long cut = cutoff;
#pragma unroll
    for (int u = 0; u < 2; u++) {
      int off = base + u * 1024 + t * 4;
      float4 v = *(const float4*)(p + off);
      float vv[4] = {v.x, v.y, v.z, v.w};
#pragma unroll
      for (int e = 0; e < 4; e++) {
        unsigned long long k =
            (((unsigned long long)flip32(vv[e])) << 32) |
            (unsigned)(~(unsigned)(seg * SEG_SZ + off + e));
        if (k > cut) {
          int pz = atomicAdd(&cnt, 1);
          if (pz < TCAP) cand[pz] = k;
        }
      }
    }
    __syncthreads();
    if (cnt > 2048) trim256(cand, &cnt, &cutoff, t);
    __syncthreads();
  }
  int n = cnt;
  int S = 256;
  while (S < n) S <<= 1;
  for (int i = n + t; i < S; i += 256) cand[i] = 0ULL;
  __syncthreads();
  bitonic_desc(cand, S, t);
  cand_g[((size_t)r * NSEG + seg) * 256 + t] = cand[t];
}

// ---------------- top-k stage 2: merge + softmax + loss + yhat ----------------
__global__ __launch_bounds__(256) void k_topk2(
    const unsigned long long* __restrict__ cand_g, const int* __restrict__ values,
    const int* __restrict__ yv, float* __restrict__ out,
    float* __restrict__ loss_arr, int* __restrict__ corr, int* __restrict__ yidx) {
  __shared__ unsigned long long cand[NSEG * 256];
  __shared__ float red[256];
  const int r = blockIdx.x, t = threadIdx.x;
  for (int i = t; i < NSEG * 256; i += 256) cand[i] = cand_g[(size_t)r * (NSEG * 256) + i];
  __syncthreads();
  bitonic_desc(cand, NSEG * 256, t);

  unsigned long long mykey = cand[t];
  int midx = (int)(~(unsigned)(mykey & 0xFFFFFFFFull));
  float msc = unflip32((unsigned)(mykey >> 32));
  int yr = yv[r];
  float mask = (values[midx] == yr) ? 1.0f : 0.0f;
  float mtop = unflip32((unsigned)(cand[0] >> 32));

  float e = expf(msc - mtop);  // TEMP == 1.0
  red[t] = e; __syncthreads();
  for (int s = 128; s > 0; s >>= 1) { if (t < s) red[t] += red[t + s]; __syncthreads(); }
  float denom = red[0]; __syncthreads();
  out[256 + r * 256 + t] = e / denom;

  red[t] = msc * mask; __syncthreads();
  for (int s = 128; s > 0; s >>= 1) { if (t < s) red[t] = fmaxf(red[t], red[t + s]); __syncthreads(); }
  float posr = red[0]; __syncthreads();

  red[t] = msc * (1.0f - mask); __syncthreads();
  for (int s = 128; s > 0; s >>= 1) { if (t < s) red[t] = fmaxf(red[t], red[t + s]); __syncthreads(); }
  float negr = red[0]; __syncthreads();

  red[t] = mask; __syncthreads();
  for (int s = 128; s > 0; s >>= 1) { if (t < s) red[t] += red[t + s]; __syncthreads(); }
  float hp = (red[0] > 0.0f) ? 1.0f : 0.0f;

  if (t == 0) {
    float pos = posr * hp;
    loss_arr[r] = fmaxf(negr - pos + 0.1f, 0.0f);
    int i0 = (int)(~(unsigned)(cand[0] & 0xFFFFFFFFull));
    out[r] = (float)values[i0];
    yidx[r] = i0;
    corr[r] = (values[i0] == yr) ? 1 : 0;
  }
}

// ---------------- age/values init ----------------
__global__ __launch_bounds__(256) void k_age(
    const float* __restrict__ age, const int* __restrict__ values,
    float* __restrict__ age_out, float* __restrict__ vals_out) {
  int i = blockIdx.x * 256 + threadIdx.x;
  age_out[i] = age[i] + 1.0f;
  vals_out[i] = (float)values[i];
}

__global__ void k_reset(const int* __restrict__ corr, const int* __restrict__ yidx,
                        float* __restrict__ age_out) {
  int t = threadIdx.x;
  if (corr[t]) age_out[yidx[t]] = 0.0f;
}

// ---------------- oldest = top-256 of age_noisy ----------------
__global__ __launch_bounds__(256) void k_oldA(
    const float* __restrict__ age_out, const float* __restrict__ un,
    unsigned long long* __restrict__ cand_o) {
  __shared__ unsigned long long cand[TCAP];
  __shared__ int cnt;
  __shared__ unsigned long long cutoff;
  __shared__ unsigned long long redu[256];
  const int t = threadIdx.x;
  const int base = blockIdx.x * 16384;
  unsigned long long mk = 0ULL;
  for (int u = 0; u < 64; u++) {
    int g = base + u * 256 + t;
    float v = age_out[g] + (2.0f * un[g] - 1.0f) * 8.0f;
    unsigned long long k =
        (((unsigned long long)flip32(v)) << 32) | (unsigned)(~(unsigned)g);
    mk = k > mk ? k : mk;
  }
  redu[t] = mk;
  __syncthreads();
  for (int s = 128; s > 0; s >>= 1) {
    if (t < s) redu[t] = (redu[t] < redu[t + s]) ? redu[t] : redu[t + s];
    __syncthreads();
  }
  if (t == 0) { cnt = 0; cutoff = redu[0] - 1ULL; }
  __syncthreads();
  for (int cb = 0; cb < 16384; cb += 2048) {
    unsigned long long cut = cutoff;
#pragma unroll
    for (int u = 0; u < 8; u++) {
      int g = base + cb + u * 256 + t;
      float v = age_out[g] + (2.0f * un[g] - 1.0f) * 8.0f;
      unsigned long long k =
          (((unsigned long long)flip32(v)) << 32) | (unsigned)(~(unsigned)g);
      if (k > cut) {
        int pz = atomicAdd(&cnt, 1);
        if (pz < TCAP) cand[pz] = k;
      }
    }
    __syncthreads();
    if (cnt > 2048) trim256(cand, &cnt, &cutoff, t);
    __syncthreads();
  }
  int n = cnt;
  int S = 256;
  while (S < n) S <<= 1;
  for (int i = n + t; i < S; i += 256) cand[i] = 0ULL;
  __syncthreads();
  bitonic_desc(cand, S, t);
  cand_o[blockIdx.x * 256 + t] = cand[t];
}

__global__ __launch_bounds__(256) void k_oldB(
    const unsigned long long* __restrict__ cand_o, const int* __restrict__ corr,
    const float* __restrict__ loss_arr, int* __restrict__ dest,
    float* __restrict__ out_loss) {
  __shared__ unsigned long long cand[4096];
  __shared__ int olds[256];
  __shared__ int pre[256];
  __shared__ float red[256];
  const int t = threadIdx.x;
  for (int i = t; i < 4096; i += 256) cand[i] = cand_o[i];
  __syncthreads();
  bitonic_desc(cand, 4096, t);
  olds[t] = (int)(~(unsigned)(cand[t] & 0xFFFFFFFFull));
  int inc = corr[t] ? 0 : 1;
  pre[t] = inc;
  __syncthreads();
  for (int off = 1; off < 256; off <<= 1) {
    int v = (t >= off) ? pre[t - off] : 0;
    __syncthreads();
    pre[t] += v;
    __syncthreads();
  }
  int rank = pre[t] - 1;
  dest[t] = inc ? olds[rank] : -1;
  red[t] = loss_arr[t]; __syncthreads();
  for (int s = 128; s > 0; s >>= 1) { if (t < s) red[t] += red[t + s]; __syncthreads(); }
  if (t == 0) *out_loss = red[0] * (1.0f / 256.0f);
}

// ---------------- keys copy + scatter updates ----------------
__global__ __launch_bounds__(256) void k_copy(const float* __restrict__ in,
                                              float* __restrict__ outp) {
  // output base is 3-float misaligned; do aligned float4 loads + scalar stores
  size_t i = (size_t)blockIdx.x * 256 + threadIdx.x;
  size_t stride = (size_t)gridDim.x * 256;
  size_t n4 = (size_t)MEM_N * DIM / 4;
  for (; i < n4; i += stride) {
    float4 v = *(const float4*)(in + i * 4);
    float* o = outp + i * 4;
    o[0] = v.x; o[1] = v.y; o[2] = v.z; o[3] = v.w;
  }
}

__global__ __launch_bounds__(256) void k_correct(
    const int* __restrict__ corr, const int* __restrict__ yidx,
    const float* __restrict__ keys, const float* __restrict__ q,
    float* __restrict__ keys_out) {
  const int r = blockIdx.x;
  if (!corr[r]) return;
  const int t = threadIdx.x;
  __shared__ float red[256];
  int d = yidx[r];
  float v = keys[(size_t)d * DIM + t] + q[r * DIM + t];
  red[t] = v * v; __syncthreads();
  for (int s = 128; s > 0; s >>= 1) { if (t < s) red[t] += red[t + s]; __syncthreads(); }
  float nrm = fmaxf(sqrtf(red[0]), 1e-12f);
  keys_out[(size_t)d * DIM + t] = v / nrm;
}

__global__ __launch_bounds__(256) void k_incorrect(
    const int* __restrict__ dest, const float* __restrict__ q,
    const int* __restrict__ yv, float* __restrict__ keys_out,
    float* __restrict__ vals_out, float* __restrict__ age_out) {
  const int r = blockIdx.x;
  int d = dest[r];
  if (d < 0) return;
  const int t = threadIdx.x;
  keys_out[(size_t)d * DIM + t] = q[r * DIM + t];
  if (t == 0) {
    vals_out[d] = (float)yv[r];
    age_out[d] = 0.0f;
  }
}

extern "C" void kernel_launch(void* const* d_in, const int* in_sizes, int n_in,
                              void* d_out, int out_size, void* d_ws, size_t ws_size,
                              hipStream_t stream) {
  const float* x = (const float*)d_in[0];
  const int* y = (const int*)d_in[1];
  const float* W = (const float*)d_in[2];
  const float* b = (const float*)d_in[3];
  const float* keys = (const float*)d_in[4];
  const int* values = (const int*)d_in[5];
  const float* age = (const float*)d_in[6];
  const float* un = (const float*)d_in[7];
  float* out = (float*)d_out;

  char* ws = (char*)d_ws;
  float* q = (float*)ws;                                     // 256 KB
  unsigned short* qhi = (unsigned short*)(ws + 262144);      // 128 KB
  unsigned short* qlo = (unsigned short*)(ws + 393216);      // 128 KB
  float* loss_arr = (float*)(ws + 524288);                   // 1 KB
  int* corr = (int*)(ws + 525312);                           // 1 KB
  int* yidx = (int*)(ws + 526336);                           // 1 KB
  unsigned long long* cand_o = (unsigned long long*)(ws + 527360);  // 32 KB
  int* dest = (int*)(ws + 560128);                           // 1 KB
  unsigned long long* cand_g = (unsigned long long*)(ws + 1048576); // 4 MB

  // d_out layout (floats): yhat[256] | softmax[65536] | loss[1] | keys[67108864]
  //                        | values[262144] | age[262144]
  const size_t LOSS_OFF = 65792, KEYS_OFF = 65793, VALS_OFF = 67174657,
               AGE_OFF = 67436801;
  float* scores = out + 65796;  // 16B-aligned scratch inside keys region
  float* keys_out = out + KEYS_OFF;
  float* vals_out = out + VALS_OFF;
  float* age_out = out + AGE_OFF;

  k_query<<<dim3(256), dim3(256), 0, stream>>>(x, W, b, q, qhi, qlo);
  k_gemm<<<dim3(4096), dim3(256), 0, stream>>>(qhi, qlo, keys, scores);
  k_topk1<<<dim3(NSEG, 256), dim3(256), 0, stream>>>(scores, cand_g);
  k_topk2<<<dim3(256), dim3(256), 0, stream>>>(cand_g, values, y, out, loss_arr, corr, yidx);
  k_age<<<dim3(1024), dim3(256), 0, stream>>>(age, values, age_out, vals_out);
  k_reset<<<dim3(1), dim3(256), 0, stream>>>(corr, yidx, age_out);
  k_oldA<<<dim3(16), dim3(256), 0, stream>>>(age_out, un, cand_o);
  k_oldB<<<dim3(1), dim3(256), 0, stream>>>(cand_o, corr, loss_arr, dest, out + LOSS_OFF);
  k_copy<<<dim3(4096), dim3(256), 0, stream>>>(keys, keys_out);
  k_correct<<<dim3(256), dim3(256), 0, stream>>>(corr, yidx, keys, q, keys_out);
  k_incorrect<<<dim3(256), dim3(256), 0, stream>>>(dest, q, y, keys_out, vals_out, age_out);
}

// Round 3
// 894.784 us; speedup vs baseline: 2.0071x; 1.2439x over previous
//
#include <hip/hip_runtime.h>

#define MEM_N 262144
#define DIM 256
#define NBATCH 256
#define TCAP 2048
#define OCAP 4096
#define NSEG 8
#define SEG_SZ 32768

typedef __attribute__((ext_vector_type(8))) short short8;
typedef __attribute__((ext_vector_type(4))) float f32x4;
typedef unsigned long long u64;

__device__ __forceinline__ unsigned short bf16_rne(float f) {
  unsigned u = __builtin_bit_cast(unsigned, f);
  u += 0x7FFFu + ((u >> 16) & 1u);
  return (unsigned short)(u >> 16);
}
__device__ __forceinline__ float bf16_f32(unsigned short h) {
  unsigned u = ((unsigned)h) << 16;
  return __builtin_bit_cast(float, u);
}
// bf16 rounded toward -inf (keeps cutoff <= true value)
__device__ __forceinline__ unsigned short bf16_floor(float f) {
  unsigned u = __builtin_bit_cast(unsigned, f);
  unsigned short h = (unsigned short)(u >> 16);
  if ((u & 0x80000000u) && (u & 0xFFFFu)) h++;
  return h;
}
__device__ __forceinline__ unsigned flip32(float f) {
  unsigned u = __builtin_bit_cast(unsigned, f);
  return u ^ ((unsigned)((int)u >> 31) | 0x80000000u);
}
__device__ __forceinline__ float unflip32(unsigned k) {
  unsigned u = (k & 0x80000000u) ? (k ^ 0x80000000u) : ~k;
  return __builtin_bit_cast(float, u);
}

// ---------------- query = normalize(x @ W^T + b), + packed-A emit ----------------
__global__ __launch_bounds__(256) void k_query(
    const float* __restrict__ x, const float* __restrict__ W,
    const float* __restrict__ b, float* __restrict__ q,
    unsigned short* __restrict__ ap_hi, unsigned short* __restrict__ ap_lo) {
  __shared__ float Wt[256][36];
  __shared__ float xs[256];
  __shared__ float red[256];
  const int r = blockIdx.x, t = threadIdx.x;
  xs[t] = x[r * DIM + t];
  float acc = b[t];
  for (int k0 = 0; k0 < DIM; k0 += 32) {
    __syncthreads();
#pragma unroll
    for (int i = 0; i < 8; i++) {
      int f = i * 256 + t;
      int j = f >> 3, c = (f & 7) * 4;
      *(float4*)&Wt[j][c] = *(const float4*)&W[j * DIM + k0 + c];
    }
    __syncthreads();
#pragma unroll
    for (int c = 0; c < 32; c++) acc = fmaf(xs[k0 + c], Wt[t][c], acc);
  }
  red[t] = acc * acc;
  __syncthreads();
  for (int s = 128; s > 0; s >>= 1) {
    if (t < s) red[t] += red[t + s];
    __syncthreads();
  }
  float nrm = fmaxf(sqrtf(red[0]), 1e-12f);
  float qv = acc / nrm;
  q[r * DIM + t] = qv;
  unsigned short h = bf16_rne(qv);
  unsigned short lo = bf16_rne(qv - bf16_f32(h));
  // packed MFMA A-fragment layout: [r16][kstep][lane][j]
  int r16 = r >> 4, s = t >> 5, hi = (t >> 3) & 3, j = t & 7;
  int l = hi * 16 + (r & 15);
  size_t off = ((size_t)(r16 * 8 + s) * 64 + l) * 8 + j;
  ap_hi[off] = h;
  ap_lo[off] = lo;
}

// ------- scores = query @ keys^T (split-bf16, 3-term MFMA) + rowmax emit -------
__global__ __launch_bounds__(256) void k_gemm(
    const unsigned short* __restrict__ ap_hi, const unsigned short* __restrict__ ap_lo,
    const float* __restrict__ keys, float* __restrict__ scores,
    unsigned short* __restrict__ rowmax) {
  __shared__ unsigned char smem[17408];
  unsigned short* Bh = (unsigned short*)smem;           // [64][40]
  unsigned short* Bl = (unsigned short*)(smem + 5120);  // [64][40]
  const int t = threadIdx.x;
  const int cb = blockIdx.x;
  const int slot0 = cb * 64;
  const int w = t >> 6, l = t & 63;
  const int lrow = l & 15, lk = (l >> 4) * 8;

  f32x4 acc[4][4];
#pragma unroll
  for (int i = 0; i < 4; ++i)
#pragma unroll
    for (int j = 0; j < 4; ++j) acc[i][j] = f32x4{0.f, 0.f, 0.f, 0.f};

  for (int k0 = 0; k0 < DIM; k0 += 32) {
    const int ks = k0 >> 5;
    // stage B: coalesced float4 keys, split to hi/lo bf16
#pragma unroll
    for (int i = 0; i < 2; i++) {
      int f = i * 256 + t;  // [0,512)
      int row = f >> 3, c = f & 7;
      float4 v = *(const float4*)(keys + (size_t)(slot0 + row) * DIM + k0 + c * 4);
      unsigned short h0 = bf16_rne(v.x), h1 = bf16_rne(v.y), h2 = bf16_rne(v.z), h3 = bf16_rne(v.w);
      unsigned short g0 = bf16_rne(v.x - bf16_f32(h0)), g1 = bf16_rne(v.y - bf16_f32(h1));
      unsigned short g2 = bf16_rne(v.z - bf16_f32(h2)), g3 = bf16_rne(v.w - bf16_f32(h3));
      uint2 hp, lp;
      hp.x = (unsigned)h0 | ((unsigned)h1 << 16);
      hp.y = (unsigned)h2 | ((unsigned)h3 << 16);
      lp.x = (unsigned)g0 | ((unsigned)g1 << 16);
      lp.y = (unsigned)g2 | ((unsigned)g3 << 16);
      *(uint2*)(Bh + row * 40 + c * 4) = hp;
      *(uint2*)(Bl + row * 40 + c * 4) = lp;
    }
    __syncthreads();
    short8 ah[4], al[4], bh[4], bl[4];
#pragma unroll
    for (int mf = 0; mf < 4; mf++) {
      size_t ab = ((size_t)((w * 4 + mf) * 8 + ks) * 64 + l) * 8;
      ah[mf] = *(const short8*)(ap_hi + ab);
      al[mf] = *(const short8*)(ap_lo + ab);
    }
#pragma unroll
    for (int nf = 0; nf < 4; nf++) {
      bh[nf] = *(const short8*)(Bh + (nf * 16 + lrow) * 40 + lk);
      bl[nf] = *(const short8*)(Bl + (nf * 16 + lrow) * 40 + lk);
    }
#pragma unroll
    for (int mf = 0; mf < 4; mf++)
#pragma unroll
      for (int nf = 0; nf < 4; nf++) {
        acc[mf][nf] = __builtin_amdgcn_mfma_f32_16x16x32_bf16(al[mf], bh[nf], acc[mf][nf], 0, 0, 0);
        acc[mf][nf] = __builtin_amdgcn_mfma_f32_16x16x32_bf16(ah[mf], bl[nf], acc[mf][nf], 0, 0, 0);
        acc[mf][nf] = __builtin_amdgcn_mfma_f32_16x16x32_bf16(ah[mf], bh[nf], acc[mf][nf], 0, 0, 0);
      }
    __syncthreads();
  }

  // rowmax over this block's 64 columns, per row (16-lane group reduce)
#pragma unroll
  for (int mf = 0; mf < 4; mf++)
#pragma unroll
    for (int j = 0; j < 4; j++) {
      float m = fmaxf(fmaxf(acc[mf][0][j], acc[mf][1][j]),
                      fmaxf(acc[mf][2][j], acc[mf][3][j]));
#pragma unroll
      for (int mk = 1; mk <= 8; mk <<= 1) m = fmaxf(m, __shfl_xor(m, mk));
      if ((l & 15) == 0) {
        int row = w * 64 + mf * 16 + (l >> 4) * 4 + j;
        rowmax[(size_t)row * 4096 + cb] = bf16_floor(m);
      }
    }

  // epilogue: LDS transpose (reuse smem) -> 16B/lane coalesced stores
  float* tr2 = ((float*)smem) + w * (16 * 68);
#pragma unroll
  for (int mf = 0; mf < 4; mf++) {
#pragma unroll
    for (int nf = 0; nf < 4; nf++)
#pragma unroll
      for (int j = 0; j < 4; j++)
        tr2[((l >> 4) * 4 + j) * 68 + nf * 16 + (l & 15)] = acc[mf][nf][j];
#pragma unroll
    for (int it = 0; it < 4; it++) {
      float4 vv = *(float4*)&tr2[(it * 4 + (l >> 4)) * 68 + 4 * (l & 15)];
      size_t row = (size_t)(w * 64 + mf * 16 + it * 4 + (l >> 4));
      *(float4*)&scores[row * MEM_N + slot0 + 4 * (l & 15)] = vv;
    }
  }
}

// ---------------- sort helpers ----------------
__device__ void bitonic_desc(u64* a, int N, int t) {
  for (int k = 2; k <= N; k <<= 1) {
    for (int j = k >> 1; j > 0; j >>= 1) {
      for (int i = t; i < N; i += 256) {
        int p = i ^ j;
        if (p > i) {
          u64 xv = a[i], yv = a[p];
          bool up = ((i & k) == 0);
          if (up ? (xv < yv) : (xv > yv)) { a[i] = yv; a[p] = xv; }
        }
      }
      __syncthreads();
    }
  }
}

// resume bitonic at phase k0 (input: aligned (k0/2)-blocks sorted, desc iff (base & k0/2)==0... standard post-(k0/2) state)
__device__ void bitonic_desc_resume(u64* a, int N, int k0, int t) {
  for (int k = k0; k <= N; k <<= 1) {
    for (int j = k >> 1; j > 0; j >>= 1) {
      for (int i = t; i < N; i += 256) {
        int p = i ^ j;
        if (p > i) {
          u64 xv = a[i], yv = a[p];
          bool up = ((i & k) == 0);
          if (up ? (xv < yv) : (xv > yv)) { a[i] = yv; a[p] = xv; }
        }
      }
      __syncthreads();
    }
  }
}

__device__ void trimN(u64* cand, int* cnt, u64* cutoff, int t, int cap) {
  int n = *cnt;
  for (int i = t; i < cap; i += 256)
    if (i >= n) cand[i] = 0ULL;
  __syncthreads();
  bitonic_desc(cand, cap, t);
  if (t == 0) { *cnt = 256; *cutoff = cand[255]; }
}

// ---------------- top-k stage 1: single filtered pass using GEMM rowmax ----------------
__global__ __launch_bounds__(256) void k_topk1(
    const float* __restrict__ scores, const unsigned short* __restrict__ rowmax,
    u64* __restrict__ cand_g) {
  __shared__ u64 cand[TCAP];
  __shared__ int cnt;
  __shared__ u64 cutoff;
  __shared__ float redf[256];
  const int seg = blockIdx.x, r = blockIdx.y, t = threadIdx.x;
  // cutoff = min over this segment's 512 column-block maxima (each is a real
  // element of the segment => >=512 guaranteed survivors, typically ~512+eps)
  const unsigned short* rm = rowmax + (size_t)r * 4096 + seg * 512;
  redf[t] = fminf(bf16_f32(rm[t]), bf16_f32(rm[t + 256]));
  __syncthreads();
  for (int s = 128; s > 0; s >>= 1) {
    if (t < s) redf[t] = fminf(redf[t], redf[t + s]);
    __syncthreads();
  }
  float cutval = redf[0];
  if (t == 0) { cnt = 0; cutoff = (((u64)flip32(cutval)) << 32) - 1ULL; }
  __syncthreads();

  const float* p = scores + (size_t)r * MEM_N + (size_t)seg * SEG_SZ;
  const u64 cut = cutoff;
  // fast path: one sweep, 4 float4 in flight per lane
  for (int base = 0; base < SEG_SZ; base += 4096) {
    float4 v[4];
#pragma unroll
    for (int u = 0; u < 4; u++) v[u] = *(const float4*)(p + base + u * 1024 + t * 4);
#pragma unroll
    for (int u = 0; u < 4; u++) {
      float vv[4] = {v[u].x, v[u].y, v[u].z, v[u].w};
      int c0 = seg * SEG_SZ + base + u * 1024 + t * 4;
#pragma unroll
      for (int e = 0; e < 4; e++) {
        u64 key = (((u64)flip32(vv[e])) << 32) | (unsigned)(~(unsigned)(c0 + e));
        if (key > cut) {
          int pz = atomicAdd(&cnt, 1);
          if (pz < TCAP) cand[pz] = key;
        }
      }
    }
  }
  __syncthreads();
  if (cnt > TCAP) {  // pathological fallback (never on this data): chunked + trims
    if (t == 0) { cnt = 0; cutoff = (((u64)flip32(cutval)) << 32) - 1ULL; }
    __syncthreads();
    for (int base = 0; base < SEG_SZ; base += 1024) {
      u64 c2 = cutoff;
      float4 v = *(const float4*)(p + base + t * 4);
      float vv[4] = {v.x, v.y, v.z, v.w};
      int c0 = seg * SEG_SZ + base + t * 4;
#pragma unroll
      for (int e = 0; e < 4; e++) {
        u64 key = (((u64)flip32(vv[e])) << 32) | (unsigned)(~(unsigned)(c0 + e));
        if (key > c2) {
          int pz = atomicAdd(&cnt, 1);
          if (pz < TCAP) cand[pz] = key;
        }
      }
      __syncthreads();
      if (cnt > 1024) trimN(cand, &cnt, &cutoff, t, TCAP);
      __syncthreads();
    }
  }
  int n = cnt < TCAP ? cnt : TCAP;
  int S = 256;
  while (S < n) S <<= 1;
  for (int i = t; i < S; i += 256)
    if (i >= n) cand[i] = 0ULL;
  __syncthreads();
  bitonic_desc(cand, S, t);
  cand_g[((size_t)r * NSEG + seg) * 256 + t] = cand[t];
}

// ---------------- top-k stage 2: merge + softmax + loss + yhat ----------------
__global__ __launch_bounds__(256) void k_topk2(
    const u64* __restrict__ cand_g, const int* __restrict__ values,
    const int* __restrict__ yv, float* __restrict__ out,
    float* __restrict__ loss_arr, int* __restrict__ corr, int* __restrict__ yidx) {
  __shared__ u64 cand[NSEG * 256];
  __shared__ float red[256];
  const int r = blockIdx.x, t = threadIdx.x;
  // load 8 desc-sorted runs, odd runs reversed -> resume bitonic at k=512
  for (int i = t; i < NSEG * 256; i += 256) {
    int j = i >> 8, jj = i & 255;
    int src = (j & 1) ? (j * 256 + 255 - jj) : i;
    cand[i] = cand_g[(size_t)r * (NSEG * 256) + src];
  }
  __syncthreads();
  bitonic_desc_resume(cand, NSEG * 256, 512, t);

  u64 mykey = cand[t];
  int midx = (int)(~(unsigned)(mykey & 0xFFFFFFFFull));
  float msc = unflip32((unsigned)(mykey >> 32));
  int yr = yv[r];
  float mask = (values[midx] == yr) ? 1.0f : 0.0f;
  float mtop = unflip32((unsigned)(cand[0] >> 32));

  float e = expf(msc - mtop);  // TEMP == 1.0
  red[t] = e; __syncthreads();
  for (int s = 128; s > 0; s >>= 1) { if (t < s) red[t] += red[t + s]; __syncthreads(); }
  float denom = red[0]; __syncthreads();
  out[256 + r * 256 + t] = e / denom;

  red[t] = msc * mask; __syncthreads();
  for (int s = 128; s > 0; s >>= 1) { if (t < s) red[t] = fmaxf(red[t], red[t + s]); __syncthreads(); }
  float posr = red[0]; __syncthreads();

  red[t] = msc * (1.0f - mask); __syncthreads();
  for (int s = 128; s > 0; s >>= 1) { if (t < s) red[t] = fmaxf(red[t], red[t + s]); __syncthreads(); }
  float negr = red[0]; __syncthreads();

  red[t] = mask; __syncthreads();
  for (int s = 128; s > 0; s >>= 1) { if (t < s) red[t] += red[t + s]; __syncthreads(); }
  float hp = (red[0] > 0.0f) ? 1.0f : 0.0f;

  if (t == 0) {
    float pos = posr * hp;
    loss_arr[r] = fmaxf(negr - pos + 0.1f, 0.0f);
    int i0 = (int)(~(unsigned)(cand[0] & 0xFFFFFFFFull));
    out[r] = (float)values[i0];
    yidx[r] = i0;
    corr[r] = (values[i0] == yr) ? 1 : 0;
  }
}

// ---------------- age/values init ----------------
__global__ __launch_bounds__(256) void k_age(
    const float* __restrict__ age, const int* __restrict__ values,
    float* __restrict__ age_out, float* __restrict__ vals_out) {
  int i = blockIdx.x * 256 + threadIdx.x;
  age_out[i] = age[i] + 1.0f;
  vals_out[i] = (float)values[i];
}

__global__ void k_reset(const int* __restrict__ corr, const int* __restrict__ yidx,
                        float* __restrict__ age_out) {
  int t = threadIdx.x;
  if (corr[t]) age_out[yidx[t]] = 0.0f;
}

// ---------------- oldest = top-256 of age_noisy ----------------
__global__ __launch_bounds__(256) void k_oldA(
    const float* __restrict__ age_out, const float* __restrict__ un,
    u64* __restrict__ cand_o) {
  __shared__ u64 cand[OCAP];
  __shared__ int cnt;
  __shared__ u64 cutoff;
  __shared__ u64 redu[256];
  const int t = threadIdx.x;
  const int base = blockIdx.x * 16384;
  u64 mk = 0ULL;
  for (int u = 0; u < 64; u++) {
    int g = base + u * 256 + t;
    float v = age_out[g] + (2.0f * un[g] - 1.0f) * 8.0f;
    u64 k = (((u64)flip32(v)) << 32) | (unsigned)(~(unsigned)g);
    mk = k > mk ? k : mk;
  }
  redu[t] = mk;
  __syncthreads();
  for (int s = 128; s > 0; s >>= 1) {
    if (t < s) redu[t] = (redu[t] < redu[t + s]) ? redu[t] : redu[t + s];
    __syncthreads();
  }
  if (t == 0) { cnt = 0; cutoff = redu[0] - 1ULL; }
  __syncthreads();
  for (int cb = 0; cb < 16384; cb += 2048) {
    u64 cut = cutoff;
#pragma unroll
    for (int u = 0; u < 8; u++) {
      int g = base + cb + u * 256 + t;
      float v = age_out[g] + (2.0f * un[g] - 1.0f) * 8.0f;
      u64 k = (((u64)flip32(v)) << 32) | (unsigned)(~(unsigned)g);
      if (k > cut) {
        int pz = atomicAdd(&cnt, 1);
        if (pz < OCAP) cand[pz] = k;
      }
    }
    __syncthreads();
    if (cnt > 2048) trimN(cand, &cnt, &cutoff, t, OCAP);
    __syncthreads();
  }
  int n = cnt < OCAP ? cnt : OCAP;
  int S = 256;
  while (S < n) S <<= 1;
  for (int i = t; i < S; i += 256)
    if (i >= n) cand[i] = 0ULL;
  __syncthreads();
  bitonic_desc(cand, S, t);
  cand_o[blockIdx.x * 256 + t] = cand[t];
}

__global__ __launch_bounds__(256) void k_oldB(
    const u64* __restrict__ cand_o, const int* __restrict__ corr,
    const float* __restrict__ loss_arr, int* __restrict__ dest,
    float* __restrict__ out_loss) {
  __shared__ u64 cand[4096];
  __shared__ int olds[256];
  __shared__ int pre[256];
  __shared__ float red[256];
  const int t = threadIdx.x;
  for (int i = t; i < 4096; i += 256) {
    int j = i >> 8, jj = i & 255;
    int src = (j & 1) ? (j * 256 + 255 - jj) : i;
    cand[i] = cand_o[src];
  }
  __syncthreads();
  bitonic_desc_resume(cand, 4096, 512, t);
  olds[t] = (int)(~(unsigned)(cand[t] & 0xFFFFFFFFull));
  int inc = corr[t] ? 0 : 1;
  pre[t] = inc;
  __syncthreads();
  for (int off = 1; off < 256; off <<= 1) {
    int v = (t >= off) ? pre[t - off] : 0;
    __syncthreads();
    pre[t] += v;
    __syncthreads();
  }
  int rank = pre[t] - 1;
  dest[t] = inc ? olds[rank] : -1;
  red[t] = loss_arr[t]; __syncthreads();
  for (int s = 128; s > 0; s >>= 1) { if (t < s) red[t] += red[t + s]; __syncthreads(); }
  if (t == 0) *out_loss = red[0] * (1.0f / 256.0f);
}

// ---------------- keys copy (aligned stores) + scatter updates ----------------
__global__ __launch_bounds__(256) void k_copy(const float* __restrict__ in,
                                              float* __restrict__ outp) {
  // outp is 16B-misaligned by 4B; outp+3 is 16B-aligned.
  const long long n4 = ((long long)MEM_N * DIM - 3) >> 2;
  long long i = (long long)blockIdx.x * 256 + threadIdx.x;
  long long stride = (long long)gridDim.x * 256;
  for (; i < n4; i += stride) {
    float s = in[3 + 4 * i];
    float4 v = *(const float4*)(in + 4 + 4 * i);
    float4 o;
    o.x = s; o.y = v.x; o.z = v.y; o.w = v.z;
    *(float4*)(outp + 3 + 4 * i) = o;
  }
  if (blockIdx.x == 0 && threadIdx.x == 0) {
    outp[0] = in[0]; outp[1] = in[1]; outp[2] = in[2];
    const long long N = (long long)MEM_N * DIM;
    outp[N - 1] = in[N - 1];
  }
}

__global__ __launch_bounds__(256) void k_correct(
    const int* __restrict__ corr, const int* __restrict__ yidx,
    const float* __restrict__ keys, const float* __restrict__ q,
    float* __restrict__ keys_out) {
  const int r = blockIdx.x;
  if (!corr[r]) return;
  const int t = threadIdx.x;
  __shared__ float red[256];
  int d = yidx[r];
  float v = keys[(size_t)d * DIM + t] + q[r * DIM + t];
  red[t] = v * v; __syncthreads();
  for (int s = 128; s > 0; s >>= 1) { if (t < s) red[t] += red[t + s]; __syncthreads(); }
  float nrm = fmaxf(sqrtf(red[0]), 1e-12f);
  keys_out[(size_t)d * DIM + t] = v / nrm;
}

__global__ __launch_bounds__(256) void k_incorrect(
    const int* __restrict__ dest, const float* __restrict__ q,
    const int* __restrict__ yv, float* __restrict__ keys_out,
    float* __restrict__ vals_out, float* __restrict__ age_out) {
  const int r = blockIdx.x;
  int d = dest[r];
  if (d < 0) return;
  const int t = threadIdx.x;
  keys_out[(size_t)d * DIM + t] = q[r * DIM + t];
  if (t == 0) {
    vals_out[d] = (float)yv[r];
    age_out[d] = 0.0f;
  }
}

extern "C" void kernel_launch(void* const* d_in, const int* in_sizes, int n_in,
                              void* d_out, int out_size, void* d_ws, size_t ws_size,
                              hipStream_t stream) {
  const float* x = (const float*)d_in[0];
  const int* y = (const int*)d_in[1];
  const float* W = (const float*)d_in[2];
  const float* b = (const float*)d_in[3];
  const float* keys = (const float*)d_in[4];
  const int* values = (const int*)d_in[5];
  const float* age = (const float*)d_in[6];
  const float* un = (const float*)d_in[7];
  float* out = (float*)d_out;

  char* ws = (char*)d_ws;
  float* q = (float*)ws;                                       // 256 KB
  unsigned short* ap_hi = (unsigned short*)(ws + 262144);      // 128 KB
  unsigned short* ap_lo = (unsigned short*)(ws + 393216);      // 128 KB
  float* loss_arr = (float*)(ws + 524288);                     // 1 KB
  int* corr = (int*)(ws + 525312);                             // 1 KB
  int* yidx = (int*)(ws + 526336);                             // 1 KB
  u64* cand_o = (u64*)(ws + 527360);                           // 32 KB
  int* dest = (int*)(ws + 560128);                             // 1 KB
  u64* cand_g = (u64*)(ws + 1048576);                          // 4 MB

  // d_out layout (floats): yhat[256] | softmax[65536] | loss[1] | keys[67108864]
  //                        | values[262144] | age[262144]
  const size_t LOSS_OFF = 65792, KEYS_OFF = 65793, VALS_OFF = 67174657,
               AGE_OFF = 67436801;
  // scores scratch: out[65792 .. 65792+MEM_N*NBATCH) -- covers loss slot (written
  // later by k_oldB) + keys region minus its last float; 16B-aligned.
  float* scores = out + 65792;
  // rowmax scratch (bf16 u16): exactly fills values+age region (2 MB), consumed by
  // k_topk1 before k_age rewrites it.
  unsigned short* rowmax = (unsigned short*)(out + VALS_OFF);
  float* keys_out = out + KEYS_OFF;
  float* vals_out = out + VALS_OFF;
  float* age_out = out + AGE_OFF;

  k_query<<<dim3(256), dim3(256), 0, stream>>>(x, W, b, q, ap_hi, ap_lo);
  k_gemm<<<dim3(4096), dim3(256), 0, stream>>>(ap_hi, ap_lo, keys, scores, rowmax);
  k_topk1<<<dim3(NSEG, 256), dim3(256), 0, stream>>>(scores, rowmax, cand_g);
  k_topk2<<<dim3(256), dim3(256), 0, stream>>>(cand_g, values, y, out, loss_arr, corr, yidx);
  k_age<<<dim3(1024), dim3(256), 0, stream>>>(age, values, age_out, vals_out);
  k_reset<<<dim3(1), dim3(256), 0, stream>>>(corr, yidx, age_out);
  k_oldA<<<dim3(16), dim3(256), 0, stream>>>(age_out, un, cand_o);
  k_oldB<<<dim3(1), dim3(256), 0, stream>>>(cand_o, corr, loss_arr, dest, out + LOSS_OFF);
  k_copy<<<dim3(4096), dim3(256), 0, stream>>>(keys, keys_out);
  k_correct<<<dim3(256), dim3(256), 0, stream>>>(corr, yidx, keys, q, keys_out);
  k_incorrect<<<dim3(256), dim3(256), 0, stream>>>(dest, q, y, keys_out, vals_out, age_out);
}

// Round 4
// 876.831 us; speedup vs baseline: 2.0482x; 1.0205x over previous
//
#include <hip/hip_runtime.h>

#define MEM_N 262144
#define DIM 256
#define NBATCH 256
#define OCAP 4096
#define NSEG 8
#define SEG_SZ 32768
#define ROWCAP 2048
#define KSEL 768

typedef __attribute__((ext_vector_type(8))) short short8;
typedef __attribute__((ext_vector_type(4))) float f32x4;
typedef unsigned long long u64;
typedef unsigned short u16;

__device__ __forceinline__ u16 bf16_rne(float f) {
  unsigned u = __builtin_bit_cast(unsigned, f);
  u += 0x7FFFu + ((u >> 16) & 1u);
  return (u16)(u >> 16);
}
__device__ __forceinline__ float bf16_f32(u16 h) {
  unsigned u = ((unsigned)h) << 16;
  return __builtin_bit_cast(float, u);
}
// bf16 rounded toward -inf (keeps stored blockmax <= true value)
__device__ __forceinline__ u16 bf16_floor(float f) {
  unsigned u = __builtin_bit_cast(unsigned, f);
  u16 h = (u16)(u >> 16);
  if ((u & 0x80000000u) && (u & 0xFFFFu)) h++;
  return h;
}
__device__ __forceinline__ unsigned flip32(float f) {
  unsigned u = __builtin_bit_cast(unsigned, f);
  return u ^ ((unsigned)((int)u >> 31) | 0x80000000u);
}
__device__ __forceinline__ float unflip32(unsigned k) {
  unsigned u = (k & 0x80000000u) ? (k ^ 0x80000000u) : ~k;
  return __builtin_bit_cast(float, u);
}
__device__ __forceinline__ u16 flip16(u16 b) {
  return (b & 0x8000u) ? (u16)~b : (u16)(b | 0x8000u);
}
__device__ __forceinline__ u16 unflip16(u16 f) {
  return (f & 0x8000u) ? (u16)(f ^ 0x8000u) : (u16)~f;
}

// ---------------- query = normalize(x @ W^T + b), + packed-A emit ----------------
__global__ __launch_bounds__(256) void k_query(
    const float* __restrict__ x, const float* __restrict__ W,
    const float* __restrict__ b, float* __restrict__ q,
    u16* __restrict__ ap_hi, u16* __restrict__ ap_lo, int* __restrict__ row_cnt) {
  __shared__ float Wt[256][36];
  __shared__ float xs[256];
  __shared__ float red[256];
  const int r = blockIdx.x, t = threadIdx.x;
  if (t == 0) row_cnt[r] = 0;
  xs[t] = x[r * DIM + t];
  float acc = b[t];
  for (int k0 = 0; k0 < DIM; k0 += 32) {
    __syncthreads();
#pragma unroll
    for (int i = 0; i < 8; i++) {
      int f = i * 256 + t;
      int j = f >> 3, c = (f & 7) * 4;
      *(float4*)&Wt[j][c] = *(const float4*)&W[j * DIM + k0 + c];
    }
    __syncthreads();
#pragma unroll
    for (int c = 0; c < 32; c++) acc = fmaf(xs[k0 + c], Wt[t][c], acc);
  }
  red[t] = acc * acc;
  __syncthreads();
  for (int s = 128; s > 0; s >>= 1) {
    if (t < s) red[t] += red[t + s];
    __syncthreads();
  }
  float nrm = fmaxf(sqrtf(red[0]), 1e-12f);
  float qv = acc / nrm;
  q[r * DIM + t] = qv;
  u16 h = bf16_rne(qv);
  u16 lo = bf16_rne(qv - bf16_f32(h));
  // packed MFMA A-fragment layout: [r16][kstep][lane][j]
  int r16 = r >> 4, s = t >> 5, hi = (t >> 3) & 3, j = t & 7;
  int l = hi * 16 + (r & 15);
  size_t off = ((size_t)(r16 * 8 + s) * 64 + l) * 8 + j;
  ap_hi[off] = h;
  ap_lo[off] = lo;
}

// ------- scores = query @ keys^T (split-bf16, 3-term MFMA) + rowmax emit -------
__global__ __launch_bounds__(256) void k_gemm(
    const u16* __restrict__ ap_hi, const u16* __restrict__ ap_lo,
    const float* __restrict__ keys, float* __restrict__ scores,
    u16* __restrict__ rowmax) {
  __shared__ unsigned char smem[17408];
  u16* Bh = (u16*)smem;           // [64][40]
  u16* Bl = (u16*)(smem + 5120);  // [64][40]
  const int t = threadIdx.x;
  const int cb = blockIdx.x;
  const int slot0 = cb * 64;
  const int w = t >> 6, l = t & 63;
  const int lrow = l & 15, lk = (l >> 4) * 8;

  f32x4 acc[4][4];
#pragma unroll
  for (int i = 0; i < 4; ++i)
#pragma unroll
    for (int j = 0; j < 4; ++j) acc[i][j] = f32x4{0.f, 0.f, 0.f, 0.f};

  for (int k0 = 0; k0 < DIM; k0 += 32) {
    const int ks = k0 >> 5;
#pragma unroll
    for (int i = 0; i < 2; i++) {
      int f = i * 256 + t;  // [0,512)
      int row = f >> 3, c = f & 7;
      float4 v = *(const float4*)(keys + (size_t)(slot0 + row) * DIM + k0 + c * 4);
      u16 h0 = bf16_rne(v.x), h1 = bf16_rne(v.y), h2 = bf16_rne(v.z), h3 = bf16_rne(v.w);
      u16 g0 = bf16_rne(v.x - bf16_f32(h0)), g1 = bf16_rne(v.y - bf16_f32(h1));
      u16 g2 = bf16_rne(v.z - bf16_f32(h2)), g3 = bf16_rne(v.w - bf16_f32(h3));
      uint2 hp, lp;
      hp.x = (unsigned)h0 | ((unsigned)h1 << 16);
      hp.y = (unsigned)h2 | ((unsigned)h3 << 16);
      lp.x = (unsigned)g0 | ((unsigned)g1 << 16);
      lp.y = (unsigned)g2 | ((unsigned)g3 << 16);
      *(uint2*)(Bh + row * 40 + c * 4) = hp;
      *(uint2*)(Bl + row * 40 + c * 4) = lp;
    }
    __syncthreads();
    short8 ah[4], al[4], bh[4], bl[4];
#pragma unroll
    for (int mf = 0; mf < 4; mf++) {
      size_t ab = ((size_t)((w * 4 + mf) * 8 + ks) * 64 + l) * 8;
      ah[mf] = *(const short8*)(ap_hi + ab);
      al[mf] = *(const short8*)(ap_lo + ab);
    }
#pragma unroll
    for (int nf = 0; nf < 4; nf++) {
      bh[nf] = *(const short8*)(Bh + (nf * 16 + lrow) * 40 + lk);
      bl[nf] = *(const short8*)(Bl + (nf * 16 + lrow) * 40 + lk);
    }
#pragma unroll
    for (int mf = 0; mf < 4; mf++)
#pragma unroll
      for (int nf = 0; nf < 4; nf++) {
        acc[mf][nf] = __builtin_amdgcn_mfma_f32_16x16x32_bf16(al[mf], bh[nf], acc[mf][nf], 0, 0, 0);
        acc[mf][nf] = __builtin_amdgcn_mfma_f32_16x16x32_bf16(ah[mf], bl[nf], acc[mf][nf], 0, 0, 0);
        acc[mf][nf] = __builtin_amdgcn_mfma_f32_16x16x32_bf16(ah[mf], bh[nf], acc[mf][nf], 0, 0, 0);
      }
    __syncthreads();
  }

  // rowmax over this block's 64 columns, per row (16-lane group reduce)
#pragma unroll
  for (int mf = 0; mf < 4; mf++)
#pragma unroll
    for (int j = 0; j < 4; j++) {
      float m = fmaxf(fmaxf(acc[mf][0][j], acc[mf][1][j]),
                      fmaxf(acc[mf][2][j], acc[mf][3][j]));
#pragma unroll
      for (int mk = 1; mk <= 8; mk <<= 1) m = fmaxf(m, __shfl_xor(m, mk));
      if ((l & 15) == 0) {
        int row = w * 64 + mf * 16 + (l >> 4) * 4 + j;
        rowmax[(size_t)row * 4096 + cb] = bf16_floor(m);
      }
    }

  // epilogue: LDS transpose (reuse smem) -> 16B/lane coalesced stores
  float* tr2 = ((float*)smem) + w * (16 * 68);
#pragma unroll
  for (int mf = 0; mf < 4; mf++) {
#pragma unroll
    for (int nf = 0; nf < 4; nf++)
#pragma unroll
      for (int j = 0; j < 4; j++)
        tr2[((l >> 4) * 4 + j) * 68 + nf * 16 + (l & 15)] = acc[mf][nf][j];
#pragma unroll
    for (int it = 0; it < 4; it++) {
      float4 vv = *(float4*)&tr2[(it * 4 + (l >> 4)) * 68 + 4 * (l & 15)];
      size_t row = (size_t)(w * 64 + mf * 16 + it * 4 + (l >> 4));
      *(float4*)&scores[row * MEM_N + slot0 + 4 * (l & 15)] = vv;
    }
  }
}

// ---- per-row cutoff = exact KSEL-th largest of 4096 bf16 block-maxima ----
// Guarantee: >= KSEL blocks have floored max >= cut, each contributes >= 1
// element >= cut  =>  >= KSEL (>=256) survivors  =>  top-256 filter is exact.
__global__ __launch_bounds__(256) void k_cut(
    const u16* __restrict__ rowmax, float* __restrict__ cut_row) {
  __shared__ int h[256];
  __shared__ int Bsh, Lsh;
  const int r = blockIdx.x, t = threadIdx.x;
  const u16* rm = rowmax + (size_t)r * 4096;
  uint4 a0 = *(const uint4*)(rm + t * 16);
  uint4 a1 = *(const uint4*)(rm + t * 16 + 8);
  u16 f[16];
  unsigned aw[8] = {a0.x, a0.y, a0.z, a0.w, a1.x, a1.y, a1.z, a1.w};
#pragma unroll
  for (int i = 0; i < 8; i++) {
    f[2 * i] = flip16((u16)(aw[i] & 0xFFFFu));
    f[2 * i + 1] = flip16((u16)(aw[i] >> 16));
  }
  h[t] = 0;
  __syncthreads();
#pragma unroll
  for (int i = 0; i < 16; i++) atomicAdd(&h[f[i] >> 8], 1);
  __syncthreads();
  for (int off = 1; off < 256; off <<= 1) {  // inclusive suffix sum
    int v = (t + off < 256) ? h[t + off] : 0;
    __syncthreads();
    h[t] += v;
    __syncthreads();
  }
  if (h[t] >= KSEL && (t == 255 || h[t + 1] < KSEL)) Bsh = t;
  __syncthreads();
  const int B = Bsh;
  const int above = (B == 255) ? 0 : h[B + 1];
  __syncthreads();
  h[t] = 0;
  __syncthreads();
#pragma unroll
  for (int i = 0; i < 16; i++)
    if ((f[i] >> 8) == B) atomicAdd(&h[f[i] & 255], 1);
  __syncthreads();
  for (int off = 1; off < 256; off <<= 1) {
    int v = (t + off < 256) ? h[t + off] : 0;
    __syncthreads();
    h[t] += v;
    __syncthreads();
  }
  if (above + h[t] >= KSEL && (t == 255 || above + h[t + 1] < KSEL)) Lsh = t;
  __syncthreads();
  if (t == 0) {
    u16 fs = (u16)((B << 8) | Lsh);
    cut_row[r] = bf16_f32(unflip16(fs));
  }
}

// ---------------- sort helpers ----------------
__device__ void bitonic_desc(u64* a, int N, int t) {
  for (int k = 2; k <= N; k <<= 1) {
    for (int j = k >> 1; j > 0; j >>= 1) {
      for (int i = t; i < N; i += 256) {
        int p = i ^ j;
        if (p > i) {
          u64 xv = a[i], yv = a[p];
          bool up = ((i & k) == 0);
          if (up ? (xv < yv) : (xv > yv)) { a[i] = yv; a[p] = xv; }
        }
      }
      __syncthreads();
    }
  }
}
__device__ void bitonic_desc_resume(u64* a, int N, int k0, int t) {
  for (int k = k0; k <= N; k <<= 1) {
    for (int j = k >> 1; j > 0; j >>= 1) {
      for (int i = t; i < N; i += 256) {
        int p = i ^ j;
        if (p > i) {
          u64 xv = a[i], yv = a[p];
          bool up = ((i & k) == 0);
          if (up ? (xv < yv) : (xv > yv)) { a[i] = yv; a[p] = xv; }
        }
      }
      __syncthreads();
    }
  }
}
__device__ void trimN(u64* cand, int* cnt, u64* cutoff, int t, int cap) {
  int n = *cnt;
  for (int i = t; i < cap; i += 256)
    if (i >= n) cand[i] = 0ULL;
  __syncthreads();
  bitonic_desc(cand, cap, t);
  if (t == 0) { *cnt = 256; *cutoff = cand[255]; }
}

// ---------- top-k stage 1: pure filtered sweep (no LDS, no sort) ----------
__global__ __launch_bounds__(256) void k_topk1(
    const float* __restrict__ scores, const float* __restrict__ cut_row,
    u64* __restrict__ cand_row, int* __restrict__ row_cnt) {
  const int seg = blockIdx.x, r = blockIdx.y, t = threadIdx.x;
  const float cutval = cut_row[r];
  const u64 cut = (((u64)flip32(cutval)) << 32) - 1ULL;  // key > cut  <=>  v >= cutval
  const float* p = scores + (size_t)r * MEM_N + (size_t)seg * SEG_SZ;
  u64* crow = cand_row + (size_t)r * ROWCAP;
  for (int base = 0; base < SEG_SZ; base += 8192) {
    float4 v[8];
#pragma unroll
    for (int u = 0; u < 8; u++) v[u] = *(const float4*)(p + base + u * 1024 + t * 4);
#pragma unroll
    for (int u = 0; u < 8; u++) {
      float vv[4] = {v[u].x, v[u].y, v[u].z, v[u].w};
      int c0 = seg * SEG_SZ + base + u * 1024 + t * 4;
#pragma unroll
      for (int e = 0; e < 4; e++) {
        u64 key = (((u64)flip32(vv[e])) << 32) | (unsigned)(~(unsigned)(c0 + e));
        if (key > cut) {
          int pos = atomicAdd(&row_cnt[r], 1);
          if (pos < ROWCAP) crow[pos] = key;
        }
      }
    }
  }
}

// ---------------- top-k stage 2: sort + softmax + loss + yhat ----------------
__global__ __launch_bounds__(256) void k_topk2(
    const u64* __restrict__ cand_row, const int* __restrict__ row_cnt,
    const int* __restrict__ values, const int* __restrict__ yv,
    float* __restrict__ out, float* __restrict__ loss_arr,
    int* __restrict__ corr, int* __restrict__ yidx) {
  __shared__ u64 buf[ROWCAP];
  __shared__ float red[256];
  const int r = blockIdx.x, t = threadIdx.x;
  int cnt = row_cnt[r];
  cnt = cnt < ROWCAP ? cnt : ROWCAP;
  int S = 256;
  while (S < cnt) S <<= 1;
  const u64* src = cand_row + (size_t)r * ROWCAP;
  for (int i = t; i < S; i += 256) buf[i] = (i < cnt) ? src[i] : 0ULL;
  __syncthreads();
  bitonic_desc(buf, S, t);

  u64 mykey = buf[t];
  int midx = mykey ? (int)(~(unsigned)(mykey & 0xFFFFFFFFull)) : 0;
  float msc = unflip32((unsigned)(mykey >> 32));
  int yr = yv[r];
  float mask = (values[midx] == yr) ? 1.0f : 0.0f;
  float mtop = unflip32((unsigned)(buf[0] >> 32));

  float e = expf(msc - mtop);  // TEMP == 1.0
  red[t] = e; __syncthreads();
  for (int s = 128; s > 0; s >>= 1) { if (t < s) red[t] += red[t + s]; __syncthreads(); }
  float denom = red[0]; __syncthreads();
  out[256 + r * 256 + t] = e / denom;

  red[t] = msc * mask; __syncthreads();
  for (int s = 128; s > 0; s >>= 1) { if (t < s) red[t] = fmaxf(red[t], red[t + s]); __syncthreads(); }
  float posr = red[0]; __syncthreads();

  red[t] = msc * (1.0f - mask); __syncthreads();
  for (int s = 128; s > 0; s >>= 1) { if (t < s) red[t] = fmaxf(red[t], red[t + s]); __syncthreads(); }
  float negr = red[0]; __syncthreads();

  red[t] = mask; __syncthreads();
  for (int s = 128; s > 0; s >>= 1) { if (t < s) red[t] += red[t + s]; __syncthreads(); }
  float hp = (red[0] > 0.0f) ? 1.0f : 0.0f;

  if (t == 0) {
    float pos = posr * hp;
    loss_arr[r] = fmaxf(negr - pos + 0.1f, 0.0f);
    int i0 = (int)(~(unsigned)(buf[0] & 0xFFFFFFFFull));
    out[r] = (float)values[i0];
    yidx[r] = i0;
    corr[r] = (values[i0] == yr) ? 1 : 0;
  }
}

// ---------------- age/values init ----------------
__global__ __launch_bounds__(256) void k_age(
    const float* __restrict__ age, const int* __restrict__ values,
    float* __restrict__ age_out, float* __restrict__ vals_out) {
  int i = blockIdx.x * 256 + threadIdx.x;
  age_out[i] = age[i] + 1.0f;
  vals_out[i] = (float)values[i];
}

__global__ void k_reset(const int* __restrict__ corr, const int* __restrict__ yidx,
                        float* __restrict__ age_out) {
  int t = threadIdx.x;
  if (corr[t]) age_out[yidx[t]] = 0.0f;
}

// ---------------- oldest = top-256 of age_noisy ----------------
__global__ __launch_bounds__(256) void k_oldA(
    const float* __restrict__ age_out, const float* __restrict__ un,
    u64* __restrict__ cand_o) {
  __shared__ u64 cand[OCAP];
  __shared__ int cnt;
  __shared__ u64 cutoff;
  __shared__ u64 redu[256];
  const int t = threadIdx.x;
  const int base = blockIdx.x * 16384;
  u64 mk = 0ULL;
  for (int u = 0; u < 64; u++) {
    int g = base + u * 256 + t;
    float v = age_out[g] + (2.0f * un[g] - 1.0f) * 8.0f;
    u64 k = (((u64)flip32(v)) << 32) | (unsigned)(~(unsigned)g);
    mk = k > mk ? k : mk;
  }
  redu[t] = mk;
  __syncthreads();
  for (int s = 128; s > 0; s >>= 1) {
    if (t < s) redu[t] = (redu[t] < redu[t + s]) ? redu[t] : redu[t + s];
    __syncthreads();
  }
  if (t == 0) { cnt = 0; cutoff = redu[0] - 1ULL; }
  __syncthreads();
  for (int cb = 0; cb < 16384; cb += 2048) {
    u64 cut = cutoff;
#pragma unroll
    for (int u = 0; u < 8; u++) {
      int g = base + cb + u * 256 + t;
      float v = age_out[g] + (2.0f * un[g] - 1.0f) * 8.0f;
      u64 k = (((u64)flip32(v)) << 32) | (unsigned)(~(unsigned)g);
      if (k > cut) {
        int pz = atomicAdd(&cnt, 1);
        if (pz < OCAP) cand[pz] = k;
      }
    }
    __syncthreads();
    if (cnt > 2048) trimN(cand, &cnt, &cutoff, t, OCAP);
    __syncthreads();
  }
  int n = cnt < OCAP ? cnt : OCAP;
  int S = 256;
  while (S < n) S <<= 1;
  for (int i = t; i < S; i += 256)
    if (i >= n) cand[i] = 0ULL;
  __syncthreads();
  bitonic_desc(cand, S, t);
  cand_o[blockIdx.x * 256 + t] = cand[t];
}

__global__ __launch_bounds__(256) void k_oldB(
    const u64* __restrict__ cand_o, const int* __restrict__ corr,
    const float* __restrict__ loss_arr, int* __restrict__ dest,
    float* __restrict__ out_loss) {
  __shared__ u64 cand[4096];
  __shared__ int olds[256];
  __shared__ int pre[256];
  __shared__ float red[256];
  const int t = threadIdx.x;
  for (int i = t; i < 4096; i += 256) {
    int j = i >> 8, jj = i & 255;
    int src = (j & 1) ? (j * 256 + 255 - jj) : i;
    cand[i] = cand_o[src];
  }
  __syncthreads();
  bitonic_desc_resume(cand, 4096, 512, t);
  olds[t] = (int)(~(unsigned)(cand[t] & 0xFFFFFFFFull));
  int inc = corr[t] ? 0 : 1;
  pre[t] = inc;
  __syncthreads();
  for (int off = 1; off < 256; off <<= 1) {
    int v = (t >= off) ? pre[t - off] : 0;
    __syncthreads();
    pre[t] += v;
    __syncthreads();
  }
  int rank = pre[t] - 1;
  dest[t] = inc ? olds[rank] : -1;
  red[t] = loss_arr[t]; __syncthreads();
  for (int s = 128; s > 0; s >>= 1) { if (t < s) red[t] += red[t + s]; __syncthreads(); }
  if (t == 0) *out_loss = red[0] * (1.0f / 256.0f);
}

// ---------------- keys copy (aligned stores) + scatter updates ----------------
__global__ __launch_bounds__(256) void k_copy(const float* __restrict__ in,
                                              float* __restrict__ outp) {
  // outp is 16B-misaligned by 4B; outp+3 is 16B-aligned.
  const long long n4 = ((long long)MEM_N * DIM - 3) >> 2;
  long long i = (long long)blockIdx.x * 256 + threadIdx.x;
  long long stride = (long long)gridDim.x * 256;
  for (; i < n4; i += stride) {
    float s = in[3 + 4 * i];
    float4 v = *(const float4*)(in + 4 + 4 * i);
    float4 o;
    o.x = s; o.y = v.x; o.z = v.y; o.w = v.z;
    *(float4*)(outp + 3 + 4 * i) = o;
  }
  if (blockIdx.x == 0 && threadIdx.x == 0) {
    outp[0] = in[0]; outp[1] = in[1]; outp[2] = in[2];
    const long long N = (long long)MEM_N * DIM;
    outp[N - 1] = in[N - 1];
  }
}

__global__ __launch_bounds__(256) void k_correct(
    const int* __restrict__ corr, const int* __restrict__ yidx,
    const float* __restrict__ keys, const float* __restrict__ q,
    float* __restrict__ keys_out) {
  const int r = blockIdx.x;
  if (!corr[r]) return;
  const int t = threadIdx.x;
  __shared__ float red[256];
  int d = yidx[r];
  float v = keys[(size_t)d * DIM + t] + q[r * DIM + t];
  red[t] = v * v; __syncthreads();
  for (int s = 128; s > 0; s >>= 1) { if (t < s) red[t] += red[t + s]; __syncthreads(); }
  float nrm = fmaxf(sqrtf(red[0]), 1e-12f);
  keys_out[(size_t)d * DIM + t] = v / nrm;
}

__global__ __launch_bounds__(256) void k_incorrect(
    const int* __restrict__ dest, const float* __restrict__ q,
    const int* __restrict__ yv, float* __restrict__ keys_out,
    float* __restrict__ vals_out, float* __restrict__ age_out) {
  const int r = blockIdx.x;
  int d = dest[r];
  if (d < 0) return;
  const int t = threadIdx.x;
  keys_out[(size_t)d * DIM + t] = q[r * DIM + t];
  if (t == 0) {
    vals_out[d] = (float)yv[r];
    age_out[d] = 0.0f;
  }
}

extern "C" void kernel_launch(void* const* d_in, const int* in_sizes, int n_in,
                              void* d_out, int out_size, void* d_ws, size_t ws_size,
                              hipStream_t stream) {
  const float* x = (const float*)d_in[0];
  const int* y = (const int*)d_in[1];
  const float* W = (const float*)d_in[2];
  const float* b = (const float*)d_in[3];
  const float* keys = (const float*)d_in[4];
  const int* values = (const int*)d_in[5];
  const float* age = (const float*)d_in[6];
  const float* un = (const float*)d_in[7];
  float* out = (float*)d_out;

  char* ws = (char*)d_ws;
  float* q = (float*)ws;                             // 256 KB
  u16* ap_hi = (u16*)(ws + 262144);                  // 128 KB
  u16* ap_lo = (u16*)(ws + 393216);                  // 128 KB
  float* loss_arr = (float*)(ws + 524288);           // 1 KB
  int* corr = (int*)(ws + 525312);                   // 1 KB
  int* yidx = (int*)(ws + 526336);                   // 1 KB
  u64* cand_o = (u64*)(ws + 527360);                 // 32 KB
  int* dest = (int*)(ws + 560128);                   // 1 KB
  int* row_cnt = (int*)(ws + 561152);                // 1 KB
  float* cut_row = (float*)(ws + 562176);            // 1 KB
  u64* cand_row = (u64*)(ws + 1048576);              // 4 MB (256 x ROWCAP)

  // d_out layout (floats): yhat[256] | softmax[65536] | loss[1] | keys[67108864]
  //                        | values[262144] | age[262144]
  const size_t LOSS_OFF = 65792, KEYS_OFF = 65793, VALS_OFF = 67174657,
               AGE_OFF = 67436801;
  // scores scratch: out[65792 .. 67174656) -- loss slot + keys region minus its
  // last float; 16B-aligned. Rewritten later by k_oldB / k_copy.
  float* scores = out + 65792;
  // rowmax scratch (bf16 u16, 2 MB): out[67174656 .. 67698944) -- last keys
  // float + values + age regions; 16B-aligned; consumed by k_cut/k_topk1 before
  // k_copy / k_age rewrite those regions.
  u16* rowmax = (u16*)(out + 67174656);
  float* keys_out = out + KEYS_OFF;
  float* vals_out = out + VALS_OFF;
  float* age_out = out + AGE_OFF;

  k_query<<<dim3(256), dim3(256), 0, stream>>>(x, W, b, q, ap_hi, ap_lo, row_cnt);
  k_gemm<<<dim3(4096), dim3(256), 0, stream>>>(ap_hi, ap_lo, keys, scores, rowmax);
  k_cut<<<dim3(256), dim3(256), 0, stream>>>(rowmax, cut_row);
  k_topk1<<<dim3(NSEG, 256), dim3(256), 0, stream>>>(scores, cut_row, cand_row, row_cnt);
  k_topk2<<<dim3(256), dim3(256), 0, stream>>>(cand_row, row_cnt, values, y, out, loss_arr, corr, yidx);
  k_age<<<dim3(1024), dim3(256), 0, stream>>>(age, values, age_out, vals_out);
  k_reset<<<dim3(1), dim3(256), 0, stream>>>(corr, yidx, age_out);
  k_oldA<<<dim3(16), dim3(256), 0, stream>>>(age_out, un, cand_o);
  k_oldB<<<dim3(1), dim3(256), 0, stream>>>(cand_o, corr, loss_arr, dest, out + LOSS_OFF);
  k_copy<<<dim3(4096), dim3(256), 0, stream>>>(keys, keys_out);
  k_correct<<<dim3(256), dim3(256), 0, stream>>>(corr, yidx, keys, q, keys_out);
  k_incorrect<<<dim3(256), dim3(256), 0, stream>>>(dest, q, y, keys_out, vals_out, age_out);
}

// Round 5
// 612.091 us; speedup vs baseline: 2.9341x; 1.4325x over previous
//
#include <hip/hip_runtime.h>

#define MEM_N 262144
#define DIM 256
#define NBATCH 256
#define OCAP 4096
#define NSEG 8
#define SEG_SZ 32768
#define ROWCAP 2048
#define KSEL 768

typedef __attribute__((ext_vector_type(8))) short short8;
typedef __attribute__((ext_vector_type(4))) float f32x4;
typedef unsigned long long u64;
typedef unsigned short u16;

__device__ __forceinline__ u16 bf16_rne(float f) {
  unsigned u = __builtin_bit_cast(unsigned, f);
  u += 0x7FFFu + ((u >> 16) & 1u);
  return (u16)(u >> 16);
}
__device__ __forceinline__ float bf16_f32(u16 h) {
  unsigned u = ((unsigned)h) << 16;
  return __builtin_bit_cast(float, u);
}
__device__ __forceinline__ u16 bf16_floor(float f) {
  unsigned u = __builtin_bit_cast(unsigned, f);
  u16 h = (u16)(u >> 16);
  if ((u & 0x80000000u) && (u & 0xFFFFu)) h++;
  return h;
}
__device__ __forceinline__ unsigned flip32(float f) {
  unsigned u = __builtin_bit_cast(unsigned, f);
  return u ^ ((unsigned)((int)u >> 31) | 0x80000000u);
}
__device__ __forceinline__ float unflip32(unsigned k) {
  unsigned u = (k & 0x80000000u) ? (k ^ 0x80000000u) : ~k;
  return __builtin_bit_cast(float, u);
}
__device__ __forceinline__ u16 flip16(u16 b) {
  return (b & 0x8000u) ? (u16)~b : (u16)(b | 0x8000u);
}
__device__ __forceinline__ u16 unflip16(u16 f) {
  return (f & 0x8000u) ? (u16)(f ^ 0x8000u) : (u16)~f;
}

// ---------------- query = normalize(x @ W^T + b), + packed-A emit ----------------
__global__ __launch_bounds__(256) void k_query(
    const float* __restrict__ x, const float* __restrict__ W,
    const float* __restrict__ b, float* __restrict__ q,
    u16* __restrict__ ap_hi, u16* __restrict__ ap_lo, int* __restrict__ row_cnt) {
  __shared__ float Wt[256][36];
  __shared__ float xs[256];
  __shared__ float red[256];
  const int r = blockIdx.x, t = threadIdx.x;
  if (t == 0) row_cnt[r] = 0;
  xs[t] = x[r * DIM + t];
  float acc = b[t];
  for (int k0 = 0; k0 < DIM; k0 += 32) {
    __syncthreads();
#pragma unroll
    for (int i = 0; i < 8; i++) {
      int f = i * 256 + t;
      int j = f >> 3, c = (f & 7) * 4;
      *(float4*)&Wt[j][c] = *(const float4*)&W[j * DIM + k0 + c];
    }
    __syncthreads();
#pragma unroll
    for (int c = 0; c < 32; c++) acc = fmaf(xs[k0 + c], Wt[t][c], acc);
  }
  red[t] = acc * acc;
  __syncthreads();
  for (int s = 128; s > 0; s >>= 1) {
    if (t < s) red[t] += red[t + s];
    __syncthreads();
  }
  float nrm = fmaxf(sqrtf(red[0]), 1e-12f);
  float qv = acc / nrm;
  q[r * DIM + t] = qv;
  u16 h = bf16_rne(qv);
  u16 lo = bf16_rne(qv - bf16_f32(h));
  // packed MFMA A-fragment layout: [r16][kstep][lane][j]
  int r16 = r >> 4, s = t >> 5, hi = (t >> 3) & 3, j = t & 7;
  int l = hi * 16 + (r & 15);
  size_t off = ((size_t)(r16 * 8 + s) * 64 + l) * 8 + j;
  ap_hi[off] = h;
  ap_lo[off] = lo;
}

// ------- scores = query @ keys^T (split-bf16, 3-term MFMA, BK=64 dbuf) -------
__global__ __launch_bounds__(256) void k_gemm(
    const u16* __restrict__ ap_hi, const u16* __restrict__ ap_lo,
    const float* __restrict__ keys, float* __restrict__ scores,
    u16* __restrict__ rowmax) {
  __shared__ u16 Bh[64][72];
  __shared__ u16 Bl[64][72];
  const int t = threadIdx.x;
  const int cb = blockIdx.x;
  const int slot0 = cb * 64;
  const int w = t >> 6, l = t & 63;
  const int lrow = l & 15, lk = (l >> 4) * 8;
  const int srow = t >> 4, sc = (t & 15) * 4;  // staging: 16 float4 per 64-col row

  f32x4 acc[4][4];
#pragma unroll
  for (int i = 0; i < 4; ++i)
#pragma unroll
    for (int j = 0; j < 4; ++j) acc[i][j] = f32x4{0.f, 0.f, 0.f, 0.f};

  float4 nx[4];
#pragma unroll
  for (int i = 0; i < 4; i++)
    nx[i] = *(const float4*)(keys + (size_t)(slot0 + srow + i * 16) * DIM + sc);

  for (int k0 = 0; k0 < DIM; k0 += 64) {
    // convert prefetched tile -> LDS
#pragma unroll
    for (int i = 0; i < 4; i++) {
      float4 v = nx[i];
      int row = srow + i * 16;
      u16 h0 = bf16_rne(v.x), h1 = bf16_rne(v.y), h2 = bf16_rne(v.z), h3 = bf16_rne(v.w);
      u16 g0 = bf16_rne(v.x - bf16_f32(h0)), g1 = bf16_rne(v.y - bf16_f32(h1));
      u16 g2 = bf16_rne(v.z - bf16_f32(h2)), g3 = bf16_rne(v.w - bf16_f32(h3));
      uint2 hp, lp;
      hp.x = (unsigned)h0 | ((unsigned)h1 << 16);
      hp.y = (unsigned)h2 | ((unsigned)h3 << 16);
      lp.x = (unsigned)g0 | ((unsigned)g1 << 16);
      lp.y = (unsigned)g2 | ((unsigned)g3 << 16);
      *(uint2*)&Bh[row][sc] = hp;
      *(uint2*)&Bl[row][sc] = lp;
    }
    __syncthreads();
    // issue next-tile global loads before MFMA block
    if (k0 + 64 < DIM) {
#pragma unroll
      for (int i = 0; i < 4; i++)
        nx[i] = *(const float4*)(keys + (size_t)(slot0 + srow + i * 16) * DIM + k0 + 64 + sc);
    }
#pragma unroll
    for (int ksl = 0; ksl < 2; ksl++) {
      const int ks = (k0 >> 5) + ksl;
      short8 ah[4], al[4], bh[4], bl[4];
#pragma unroll
      for (int mf = 0; mf < 4; mf++) {
        size_t ab = ((size_t)((w * 4 + mf) * 8 + ks) * 64 + l) * 8;
        ah[mf] = *(const short8*)(ap_hi + ab);
        al[mf] = *(const short8*)(ap_lo + ab);
      }
#pragma unroll
      for (int nf = 0; nf < 4; nf++) {
        bh[nf] = *(const short8*)(&Bh[nf * 16 + lrow][ksl * 32 + lk]);
        bl[nf] = *(const short8*)(&Bl[nf * 16 + lrow][ksl * 32 + lk]);
      }
#pragma unroll
      for (int mf = 0; mf < 4; mf++)
#pragma unroll
        for (int nf = 0; nf < 4; nf++) {
          acc[mf][nf] = __builtin_amdgcn_mfma_f32_16x16x32_bf16(al[mf], bh[nf], acc[mf][nf], 0, 0, 0);
          acc[mf][nf] = __builtin_amdgcn_mfma_f32_16x16x32_bf16(ah[mf], bl[nf], acc[mf][nf], 0, 0, 0);
          acc[mf][nf] = __builtin_amdgcn_mfma_f32_16x16x32_bf16(ah[mf], bh[nf], acc[mf][nf], 0, 0, 0);
        }
    }
    __syncthreads();
  }

  // rowmax over this block's 64 columns, per row (16-lane group reduce)
#pragma unroll
  for (int mf = 0; mf < 4; mf++)
#pragma unroll
    for (int j = 0; j < 4; j++) {
      float m = fmaxf(fmaxf(acc[mf][0][j], acc[mf][1][j]),
                      fmaxf(acc[mf][2][j], acc[mf][3][j]));
#pragma unroll
      for (int mk = 1; mk <= 8; mk <<= 1) m = fmaxf(m, __shfl_xor(m, mk));
      if ((l & 15) == 0) {
        int row = w * 64 + mf * 16 + (l >> 4) * 4 + j;
        rowmax[(size_t)row * 4096 + cb] = bf16_floor(m);
      }
    }

  // epilogue: LDS transpose (reuse Bh/Bl region) -> 16B/lane coalesced stores
  float* tr2 = ((float*)&Bh[0][0]) + w * (16 * 68);
#pragma unroll
  for (int mf = 0; mf < 4; mf++) {
    __syncthreads();
#pragma unroll
    for (int nf = 0; nf < 4; nf++)
#pragma unroll
      for (int j = 0; j < 4; j++)
        tr2[((l >> 4) * 4 + j) * 68 + nf * 16 + (l & 15)] = acc[mf][nf][j];
    __syncthreads();
#pragma unroll
    for (int it = 0; it < 4; it++) {
      float4 vv = *(float4*)&tr2[(it * 4 + (l >> 4)) * 68 + 4 * (l & 15)];
      size_t row = (size_t)(w * 64 + mf * 16 + it * 4 + (l >> 4));
      *(float4*)&scores[row * MEM_N + slot0 + 4 * (l & 15)] = vv;
    }
  }
}

// ---- per-row cutoff = exact KSEL-th largest of 4096 bf16 block-maxima ----
__global__ __launch_bounds__(256) void k_cut(
    const u16* __restrict__ rowmax, float* __restrict__ cut_row) {
  __shared__ int h[256];
  __shared__ int Bsh, Lsh;
  const int r = blockIdx.x, t = threadIdx.x;
  const u16* rm = rowmax + (size_t)r * 4096;
  uint4 a0 = *(const uint4*)(rm + t * 16);
  uint4 a1 = *(const uint4*)(rm + t * 16 + 8);
  u16 f[16];
  unsigned aw[8] = {a0.x, a0.y, a0.z, a0.w, a1.x, a1.y, a1.z, a1.w};
#pragma unroll
  for (int i = 0; i < 8; i++) {
    f[2 * i] = flip16((u16)(aw[i] & 0xFFFFu));
    f[2 * i + 1] = flip16((u16)(aw[i] >> 16));
  }
  h[t] = 0;
  __syncthreads();
#pragma unroll
  for (int i = 0; i < 16; i++) atomicAdd(&h[f[i] >> 8], 1);
  __syncthreads();
  for (int off = 1; off < 256; off <<= 1) {
    int v = (t + off < 256) ? h[t + off] : 0;
    __syncthreads();
    h[t] += v;
    __syncthreads();
  }
  if (h[t] >= KSEL && (t == 255 || h[t + 1] < KSEL)) Bsh = t;
  __syncthreads();
  const int B = Bsh;
  const int above = (B == 255) ? 0 : h[B + 1];
  __syncthreads();
  h[t] = 0;
  __syncthreads();
#pragma unroll
  for (int i = 0; i < 16; i++)
    if ((f[i] >> 8) == B) atomicAdd(&h[f[i] & 255], 1);
  __syncthreads();
  for (int off = 1; off < 256; off <<= 1) {
    int v = (t + off < 256) ? h[t + off] : 0;
    __syncthreads();
    h[t] += v;
    __syncthreads();
  }
  if (above + h[t] >= KSEL && (t == 255 || above + h[t + 1] < KSEL)) Lsh = t;
  __syncthreads();
  if (t == 0) {
    u16 fs = (u16)((B << 8) | Lsh);
    cut_row[r] = bf16_f32(unflip16(fs));
  }
}

// ---------------- sort helpers ----------------
__device__ void bitonic_desc(u64* a, int N, int t) {
  for (int k = 2; k <= N; k <<= 1) {
    for (int j = k >> 1; j > 0; j >>= 1) {
      for (int i = t; i < N; i += 256) {
        int p = i ^ j;
        if (p > i) {
          u64 xv = a[i], yv = a[p];
          bool up = ((i & k) == 0);
          if (up ? (xv < yv) : (xv > yv)) { a[i] = yv; a[p] = xv; }
        }
      }
      __syncthreads();
    }
  }
}
__device__ void bitonic_desc_resume(u64* a, int N, int k0, int t) {
  for (int k = k0; k <= N; k <<= 1) {
    for (int j = k >> 1; j > 0; j >>= 1) {
      for (int i = t; i < N; i += 256) {
        int p = i ^ j;
        if (p > i) {
          u64 xv = a[i], yv = a[p];
          bool up = ((i & k) == 0);
          if (up ? (xv < yv) : (xv > yv)) { a[i] = yv; a[p] = xv; }
        }
      }
      __syncthreads();
    }
  }
}
__device__ void trimN(u64* cand, int* cnt, u64* cutoff, int t, int cap) {
  int n = *cnt;
  for (int i = t; i < cap; i += 256)
    if (i >= n) cand[i] = 0ULL;
  __syncthreads();
  bitonic_desc(cand, cap, t);
  if (t == 0) { *cnt = 256; *cutoff = cand[255]; }
}

// ---- sweep: filtered top-k candidate collection (LDS-compacted) + keys copy ----
__global__ __launch_bounds__(256) void k_sweep(
    const float* __restrict__ scores, const float* __restrict__ cut_row,
    const float* __restrict__ keys, u64* __restrict__ cand_row,
    int* __restrict__ row_cnt, float* __restrict__ keys_out) {
  __shared__ u64 lbuf[2048];
  __shared__ int lcnt, gbase;
  const int seg = blockIdx.x, r = blockIdx.y, t = threadIdx.x;
  if (t == 0) lcnt = 0;
  __syncthreads();
  const float cutval = cut_row[r];
  const float* p = scores + (size_t)r * MEM_N + (size_t)seg * SEG_SZ;

  // phase A: filtered sweep, LDS compaction (no global atomics in loop)
  for (int base = 0; base < SEG_SZ; base += 8192) {
    float4 v[8];
#pragma unroll
    for (int u = 0; u < 8; u++) v[u] = *(const float4*)(p + base + u * 1024 + t * 4);
#pragma unroll
    for (int u = 0; u < 8; u++) {
      float vv[4] = {v[u].x, v[u].y, v[u].z, v[u].w};
      int c0 = seg * SEG_SZ + base + u * 1024 + t * 4;
#pragma unroll
      for (int e = 0; e < 4; e++) {
        if (vv[e] >= cutval) {
          u64 key = (((u64)flip32(vv[e])) << 32) | (unsigned)(~(unsigned)(c0 + e));
          int pz = atomicAdd(&lcnt, 1);
          if (pz < 2048) lbuf[pz] = key;
        }
      }
    }
  }
  __syncthreads();
  int n = lcnt < 2048 ? lcnt : 2048;
  if (t == 0) gbase = atomicAdd(&row_cnt[r], n);
  __syncthreads();
  const int gb = gbase;
  u64* crow = cand_row + (size_t)r * ROWCAP;
  for (int i = t; i < n; i += 256) {
    int gp = gb + i;
    if (gp < ROWCAP) crow[gp] = lbuf[i];
  }

  // phase B: keys copy into the exact region this block just read.
  // kflat range [b, b+32768), b % 4 == 3 -> store-aligned float4 at kflat=b+4i,
  // recombined from scalar keys[b+4i] + aligned float4 keys[b+4i+1].
  const long long b = (long long)r * MEM_N + (long long)seg * SEG_SZ - 1;
  for (int i = t; i < 8192; i += 256) {
    long long k4 = b + 4LL * i;
    if (k4 < 0) continue;  // only block (0,0) i=0
    float s = keys[k4];
    float4 v = *(const float4*)(keys + k4 + 1);
    float4 o;
    o.x = s; o.y = v.x; o.z = v.y; o.w = v.z;
    *(float4*)(keys_out + k4) = o;
  }
  if (r == 0 && seg == 0 && t == 0) {
    keys_out[0] = keys[0]; keys_out[1] = keys[1]; keys_out[2] = keys[2];
  }
}

// ---------------- top-k stage 2: sort + softmax + loss + yhat ----------------
__global__ __launch_bounds__(256) void k_topk2(
    const u64* __restrict__ cand_row, const int* __restrict__ row_cnt,
    const int* __restrict__ values, const int* __restrict__ yv,
    float* __restrict__ out, float* __restrict__ loss_arr,
    int* __restrict__ corr, int* __restrict__ yidx) {
  __shared__ u64 buf[ROWCAP];
  __shared__ float red[256];
  const int r = blockIdx.x, t = threadIdx.x;
  int cnt = row_cnt[r];
  cnt = cnt < ROWCAP ? cnt : ROWCAP;
  int S = 256;
  while (S < cnt) S <<= 1;
  const u64* src = cand_row + (size_t)r * ROWCAP;
  for (int i = t; i < S; i += 256) buf[i] = (i < cnt) ? src[i] : 0ULL;
  __syncthreads();
  bitonic_desc(buf, S, t);

  u64 mykey = buf[t];
  int midx = mykey ? (int)(~(unsigned)(mykey & 0xFFFFFFFFull)) : 0;
  float msc = unflip32((unsigned)(mykey >> 32));
  int yr = yv[r];
  float mask = (values[midx] == yr) ? 1.0f : 0.0f;
  float mtop = unflip32((unsigned)(buf[0] >> 32));

  float e = expf(msc - mtop);  // TEMP == 1.0
  red[t] = e; __syncthreads();
  for (int s = 128; s > 0; s >>= 1) { if (t < s) red[t] += red[t + s]; __syncthreads(); }
  float denom = red[0]; __syncthreads();
  out[256 + r * 256 + t] = e / denom;

  red[t] = msc * mask; __syncthreads();
  for (int s = 128; s > 0; s >>= 1) { if (t < s) red[t] = fmaxf(red[t], red[t + s]); __syncthreads(); }
  float posr = red[0]; __syncthreads();

  red[t] = msc * (1.0f - mask); __syncthreads();
  for (int s = 128; s > 0; s >>= 1) { if (t < s) red[t] = fmaxf(red[t], red[t + s]); __syncthreads(); }
  float negr = red[0]; __syncthreads();

  red[t] = mask; __syncthreads();
  for (int s = 128; s > 0; s >>= 1) { if (t < s) red[t] += red[t + s]; __syncthreads(); }
  float hp = (red[0] > 0.0f) ? 1.0f : 0.0f;

  if (t == 0) {
    float pos = posr * hp;
    loss_arr[r] = fmaxf(negr - pos + 0.1f, 0.0f);
    int i0 = (int)(~(unsigned)(buf[0] & 0xFFFFFFFFull));
    out[r] = (float)values[i0];
    yidx[r] = i0;
    corr[r] = (values[i0] == yr) ? 1 : 0;
  }
}

// ---------------- age/values init ----------------
__global__ __launch_bounds__(256) void k_age(
    const float* __restrict__ age, const int* __restrict__ values,
    float* __restrict__ age_out, float* __restrict__ vals_out) {
  int i = blockIdx.x * 256 + threadIdx.x;
  age_out[i] = age[i] + 1.0f;
  vals_out[i] = (float)values[i];
}

__global__ void k_reset(const int* __restrict__ corr, const int* __restrict__ yidx,
                        float* __restrict__ age_out, const float* __restrict__ keys,
                        float* __restrict__ keys_out) {
  int t = threadIdx.x;
  if (corr[t]) age_out[yidx[t]] = 0.0f;
  if (t == 255) {
    const long long N = (long long)MEM_N * DIM;
    keys_out[N - 1] = keys[N - 1];  // only element k_sweep's copy doesn't cover
  }
}

// ---------------- oldest = top-256 of age_noisy ----------------
__global__ __launch_bounds__(256) void k_oldA(
    const float* __restrict__ age_out, const float* __restrict__ un,
    u64* __restrict__ cand_o) {
  __shared__ u64 cand[OCAP];
  __shared__ int cnt;
  __shared__ u64 cutoff;
  __shared__ u64 redu[256];
  const int t = threadIdx.x;
  const int base = blockIdx.x * 16384;
  u64 mk = 0ULL;
  for (int u = 0; u < 64; u++) {
    int g = base + u * 256 + t;
    float v = age_out[g] + (2.0f * un[g] - 1.0f) * 8.0f;
    u64 k = (((u64)flip32(v)) << 32) | (unsigned)(~(unsigned)g);
    mk = k > mk ? k : mk;
  }
  redu[t] = mk;
  __syncthreads();
  for (int s = 128; s > 0; s >>= 1) {
    if (t < s) redu[t] = (redu[t] < redu[t + s]) ? redu[t] : redu[t + s];
    __syncthreads();
  }
  if (t == 0) { cnt = 0; cutoff = redu[0] - 1ULL; }
  __syncthreads();
  for (int cb = 0; cb < 16384; cb += 2048) {
    u64 cut = cutoff;
#pragma unroll
    for (int u = 0; u < 8; u++) {
      int g = base + cb + u * 256 + t;
      float v = age_out[g] + (2.0f * un[g] - 1.0f) * 8.0f;
      u64 k = (((u64)flip32(v)) << 32) | (unsigned)(~(unsigned)g);
      if (k > cut) {
        int pz = atomicAdd(&cnt, 1);
        if (pz < OCAP) cand[pz] = k;
      }
    }
    __syncthreads();
    if (cnt > 2048) trimN(cand, &cnt, &cutoff, t, OCAP);
    __syncthreads();
  }
  int n = cnt < OCAP ? cnt : OCAP;
  int S = 256;
  while (S < n) S <<= 1;
  for (int i = t; i < S; i += 256)
    if (i >= n) cand[i] = 0ULL;
  __syncthreads();
  bitonic_desc(cand, S, t);
  cand_o[blockIdx.x * 256 + t] = cand[t];
}

__global__ __launch_bounds__(256) void k_oldB(
    const u64* __restrict__ cand_o, const int* __restrict__ corr,
    const float* __restrict__ loss_arr, int* __restrict__ dest,
    float* __restrict__ out_loss) {
  __shared__ u64 cand[4096];
  __shared__ int olds[256];
  __shared__ int pre[256];
  __shared__ float red[256];
  const int t = threadIdx.x;
  for (int i = t; i < 4096; i += 256) {
    int j = i >> 8, jj = i & 255;
    int src = (j & 1) ? (j * 256 + 255 - jj) : i;
    cand[i] = cand_o[src];
  }
  __syncthreads();
  bitonic_desc_resume(cand, 4096, 512, t);
  olds[t] = (int)(~(unsigned)(cand[t] & 0xFFFFFFFFull));
  int inc = corr[t] ? 0 : 1;
  pre[t] = inc;
  __syncthreads();
  for (int off = 1; off < 256; off <<= 1) {
    int v = (t >= off) ? pre[t - off] : 0;
    __syncthreads();
    pre[t] += v;
    __syncthreads();
  }
  int rank = pre[t] - 1;
  dest[t] = inc ? olds[rank] : -1;
  red[t] = loss_arr[t]; __syncthreads();
  for (int s = 128; s > 0; s >>= 1) { if (t < s) red[t] += red[t + s]; __syncthreads(); }
  if (t == 0) *out_loss = red[0] * (1.0f / 256.0f);
}

// ---------------- scatter updates ----------------
__global__ __launch_bounds__(256) void k_correct(
    const int* __restrict__ corr, const int* __restrict__ yidx,
    const float* __restrict__ keys, const float* __restrict__ q,
    float* __restrict__ keys_out) {
  const int r = blockIdx.x;
  if (!corr[r]) return;
  const int t = threadIdx.x;
  __shared__ float red[256];
  int d = yidx[r];
  float v = keys[(size_t)d * DIM + t] + q[r * DIM + t];
  red[t] = v * v; __syncthreads();
  for (int s = 128; s > 0; s >>= 1) { if (t < s) red[t] += red[t + s]; __syncthreads(); }
  float nrm = fmaxf(sqrtf(red[0]), 1e-12f);
  keys_out[(size_t)d * DIM + t] = v / nrm;
}

__global__ __launch_bounds__(256) void k_incorrect(
    const int* __restrict__ dest, const float* __restrict__ q,
    const int* __restrict__ yv, float* __restrict__ keys_out,
    float* __restrict__ vals_out, float* __restrict__ age_out) {
  const int r = blockIdx.x;
  int d = dest[r];
  if (d < 0) return;
  const int t = threadIdx.x;
  keys_out[(size_t)d * DIM + t] = q[r * DIM + t];
  if (t == 0) {
    vals_out[d] = (float)yv[r];
    age_out[d] = 0.0f;
  }
}

extern "C" void kernel_launch(void* const* d_in, const int* in_sizes, int n_in,
                              void* d_out, int out_size, void* d_ws, size_t ws_size,
                              hipStream_t stream) {
  const float* x = (const float*)d_in[0];
  const int* y = (const int*)d_in[1];
  const float* W = (const float*)d_in[2];
  const float* b = (const float*)d_in[3];
  const float* keys = (const float*)d_in[4];
  const int* values = (const int*)d_in[5];
  const float* age = (const float*)d_in[6];
  const float* un = (const float*)d_in[7];
  float* out = (float*)d_out;

  char* ws = (char*)d_ws;
  float* q = (float*)ws;                             // 256 KB
  u16* ap_hi = (u16*)(ws + 262144);                  // 128 KB
  u16* ap_lo = (u16*)(ws + 393216);                  // 128 KB
  float* loss_arr = (float*)(ws + 524288);           // 1 KB
  int* corr = (int*)(ws + 525312);                   // 1 KB
  int* yidx = (int*)(ws + 526336);                   // 1 KB
  u64* cand_o = (u64*)(ws + 527360);                 // 32 KB
  int* dest = (int*)(ws + 560128);                   // 1 KB
  int* row_cnt = (int*)(ws + 561152);                // 1 KB
  float* cut_row = (float*)(ws + 562176);            // 1 KB
  u64* cand_row = (u64*)(ws + 1048576);              // 4 MB (256 x ROWCAP)

  // d_out layout (floats): yhat[256] | softmax[65536] | loss[1] | keys[67108864]
  //                        | values[262144] | age[262144]
  const size_t LOSS_OFF = 65792, KEYS_OFF = 65793, VALS_OFF = 67174657,
               AGE_OFF = 67436801;
  float* scores = out + 65792;          // 256 MB scratch over loss+keys region
  u16* rowmax = (u16*)(out + 67174656); // 2 MB scratch over last-key+values+age
  float* keys_out = out + KEYS_OFF;
  float* vals_out = out + VALS_OFF;
  float* age_out = out + AGE_OFF;

  k_query<<<dim3(256), dim3(256), 0, stream>>>(x, W, b, q, ap_hi, ap_lo, row_cnt);
  k_gemm<<<dim3(4096), dim3(256), 0, stream>>>(ap_hi, ap_lo, keys, scores, rowmax);
  k_cut<<<dim3(256), dim3(256), 0, stream>>>(rowmax, cut_row);
  k_sweep<<<dim3(NSEG, 256), dim3(256), 0, stream>>>(scores, cut_row, keys, cand_row, row_cnt, keys_out);
  k_topk2<<<dim3(256), dim3(256), 0, stream>>>(cand_row, row_cnt, values, y, out, loss_arr, corr, yidx);
  k_age<<<dim3(1024), dim3(256), 0, stream>>>(age, values, age_out, vals_out);
  k_reset<<<dim3(1), dim3(256), 0, stream>>>(corr, yidx, age_out, keys, keys_out);
  k_oldA<<<dim3(16), dim3(256), 0, stream>>>(age_out, un, cand_o);
  k_oldB<<<dim3(1), dim3(256), 0, stream>>>(cand_o, corr, loss_arr, dest, out + LOSS_OFF);
  k_correct<<<dim3(256), dim3(256), 0, stream>>>(corr, yidx, keys, q, keys_out);
  k_incorrect<<<dim3(256), dim3(256), 0, stream>>>(dest, q, y, keys_out, vals_out, age_out);
}

// Round 6
// 593.013 us; speedup vs baseline: 3.0285x; 1.0322x over previous
//
#include <hip/hip_runtime.h>

#define MEM_N 262144
#define DIM 256
#define NBATCH 256
#define OCAP 4096
#define NSEG 8
#define SEG_SZ 32768
#define ROWCAP 2048
#define KSEL 768

typedef __attribute__((ext_vector_type(8))) short short8;
typedef __attribute__((ext_vector_type(4))) float f32x4;
typedef unsigned long long u64;
typedef unsigned short u16;

__device__ __forceinline__ u16 bf16_rne(float f) {
  unsigned u = __builtin_bit_cast(unsigned, f);
  u += 0x7FFFu + ((u >> 16) & 1u);
  return (u16)(u >> 16);
}
__device__ __forceinline__ float bf16_f32(u16 h) {
  unsigned u = ((unsigned)h) << 16;
  return __builtin_bit_cast(float, u);
}
__device__ __forceinline__ u16 bf16_floor(float f) {
  unsigned u = __builtin_bit_cast(unsigned, f);
  u16 h = (u16)(u >> 16);
  if ((u & 0x80000000u) && (u & 0xFFFFu)) h++;
  return h;
}
__device__ __forceinline__ unsigned flip32(float f) {
  unsigned u = __builtin_bit_cast(unsigned, f);
  return u ^ ((unsigned)((int)u >> 31) | 0x80000000u);
}
__device__ __forceinline__ float unflip32(unsigned k) {
  unsigned u = (k & 0x80000000u) ? (k ^ 0x80000000u) : ~k;
  return __builtin_bit_cast(float, u);
}
__device__ __forceinline__ u16 flip16(u16 b) {
  return (b & 0x8000u) ? (u16)~b : (u16)(b | 0x8000u);
}
__device__ __forceinline__ u16 unflip16(u16 f) {
  return (f & 0x8000u) ? (u16)(f ^ 0x8000u) : (u16)~f;
}

// ---------------- query = normalize(x @ W^T + b), + packed-A emit ----------------
__global__ __launch_bounds__(256) void k_query(
    const float* __restrict__ x, const float* __restrict__ W,
    const float* __restrict__ b, float* __restrict__ q,
    u16* __restrict__ ap_hi, u16* __restrict__ ap_lo, int* __restrict__ row_cnt) {
  __shared__ float Wt[256][36];
  __shared__ float xs[256];
  __shared__ float red[256];
  const int r = blockIdx.x, t = threadIdx.x;
  if (t == 0) row_cnt[r] = 0;
  xs[t] = x[r * DIM + t];
  float acc = b[t];
  for (int k0 = 0; k0 < DIM; k0 += 32) {
    __syncthreads();
#pragma unroll
    for (int i = 0; i < 8; i++) {
      int f = i * 256 + t;
      int j = f >> 3, c = (f & 7) * 4;
      *(float4*)&Wt[j][c] = *(const float4*)&W[j * DIM + k0 + c];
    }
    __syncthreads();
#pragma unroll
    for (int c = 0; c < 32; c++) acc = fmaf(xs[k0 + c], Wt[t][c], acc);
  }
  red[t] = acc * acc;
  __syncthreads();
  for (int s = 128; s > 0; s >>= 1) {
    if (t < s) red[t] += red[t + s];
    __syncthreads();
  }
  float nrm = fmaxf(sqrtf(red[0]), 1e-12f);
  float qv = acc / nrm;
  q[r * DIM + t] = qv;
  u16 h = bf16_rne(qv);
  u16 lo = bf16_rne(qv - bf16_f32(h));
  // packed MFMA A-fragment layout: [r16][kstep][lane][j]
  int r16 = r >> 4, s = t >> 5, hi = (t >> 3) & 3, j = t & 7;
  int l = hi * 16 + (r & 15);
  size_t off = ((size_t)(r16 * 8 + s) * 64 + l) * 8 + j;
  ap_hi[off] = h;
  ap_lo[off] = lo;
}

// --- scores = (q_hi + q_lo) @ bf16(keys)^T  (2-term MFMA, BK=128 dbuf) ---
__global__ __launch_bounds__(256) void k_gemm(
    const u16* __restrict__ ap_hi, const u16* __restrict__ ap_lo,
    const float* __restrict__ keys, float* __restrict__ scores,
    u16* __restrict__ rowmax) {
  // fragment-ordered bf16 keys: shorts[(kq*64 + row)*8 + j]  (conflict-free)
  __shared__ u16 Bf[2][8192];
  const int t = threadIdx.x;
  const int cb = blockIdx.x;
  const int slot0 = cb * 64;
  const int w = t >> 6, l = t & 63;
  const int lrow = l & 15, lq = l >> 4;
  const int srow = t >> 2, sk = t & 3;
  const float* kp = keys + (size_t)(slot0 + srow) * DIM + sk * 8;

  f32x4 acc[4][4];
#pragma unroll
  for (int i = 0; i < 4; ++i)
#pragma unroll
    for (int j = 0; j < 4; ++j) acc[i][j] = f32x4{0.f, 0.f, 0.f, 0.f};

  // stage tile 0 (k 0..127)
  {
    float4 va[4][2];
#pragma unroll
    for (int j = 0; j < 4; j++) {
      va[j][0] = *(const float4*)(kp + j * 32);
      va[j][1] = *(const float4*)(kp + j * 32 + 4);
    }
#pragma unroll
    for (int j = 0; j < 4; j++) {
      float f0[8] = {va[j][0].x, va[j][0].y, va[j][0].z, va[j][0].w,
                     va[j][1].x, va[j][1].y, va[j][1].z, va[j][1].w};
      uint4 pk;
      unsigned* pw = (unsigned*)&pk;
#pragma unroll
      for (int i = 0; i < 4; i++)
        pw[i] = (unsigned)bf16_rne(f0[2 * i]) | ((unsigned)bf16_rne(f0[2 * i + 1]) << 16);
      *(uint4*)&Bf[0][((j * 4 + sk) * 64 + srow) * 8] = pk;
    }
  }
  __syncthreads();
  // prefetch tile 1 (k 128..255)
  float4 vb[4][2];
#pragma unroll
  for (int j = 0; j < 4; j++) {
    vb[j][0] = *(const float4*)(kp + 128 + j * 32);
    vb[j][1] = *(const float4*)(kp + 128 + j * 32 + 4);
  }
  // MFMA tile 0
#pragma unroll
  for (int ksl = 0; ksl < 4; ksl++) {
    short8 bh[4], ah[4], al[4];
#pragma unroll
    for (int nf = 0; nf < 4; nf++)
      bh[nf] = *(const short8*)(&Bf[0][((ksl * 4 + lq) * 64 + nf * 16 + lrow) * 8]);
#pragma unroll
    for (int mf = 0; mf < 4; mf++) {
      size_t ab = ((size_t)((w * 4 + mf) * 8 + ksl) * 64 + l) * 8;
      ah[mf] = *(const short8*)(ap_hi + ab);
      al[mf] = *(const short8*)(ap_lo + ab);
    }
#pragma unroll
    for (int mf = 0; mf < 4; mf++)
#pragma unroll
      for (int nf = 0; nf < 4; nf++) {
        acc[mf][nf] = __builtin_amdgcn_mfma_f32_16x16x32_bf16(al[mf], bh[nf], acc[mf][nf], 0, 0, 0);
        acc[mf][nf] = __builtin_amdgcn_mfma_f32_16x16x32_bf16(ah[mf], bh[nf], acc[mf][nf], 0, 0, 0);
      }
  }
  // stage tile 1 (Bf[1] disjoint from Bf[0] -> no barrier before writes)
#pragma unroll
  for (int j = 0; j < 4; j++) {
    float f0[8] = {vb[j][0].x, vb[j][0].y, vb[j][0].z, vb[j][0].w,
                   vb[j][1].x, vb[j][1].y, vb[j][1].z, vb[j][1].w};
    uint4 pk;
    unsigned* pw = (unsigned*)&pk;
#pragma unroll
    for (int i = 0; i < 4; i++)
      pw[i] = (unsigned)bf16_rne(f0[2 * i]) | ((unsigned)bf16_rne(f0[2 * i + 1]) << 16);
    *(uint4*)&Bf[1][((j * 4 + sk) * 64 + srow) * 8] = pk;
  }
  __syncthreads();
  // MFMA tile 1
#pragma unroll
  for (int ksl = 0; ksl < 4; ksl++) {
    short8 bh[4], ah[4], al[4];
#pragma unroll
    for (int nf = 0; nf < 4; nf++)
      bh[nf] = *(const short8*)(&Bf[1][((ksl * 4 + lq) * 64 + nf * 16 + lrow) * 8]);
#pragma unroll
    for (int mf = 0; mf < 4; mf++) {
      size_t ab = ((size_t)((w * 4 + mf) * 8 + 4 + ksl) * 64 + l) * 8;
      ah[mf] = *(const short8*)(ap_hi + ab);
      al[mf] = *(const short8*)(ap_lo + ab);
    }
#pragma unroll
    for (int mf = 0; mf < 4; mf++)
#pragma unroll
      for (int nf = 0; nf < 4; nf++) {
        acc[mf][nf] = __builtin_amdgcn_mfma_f32_16x16x32_bf16(al[mf], bh[nf], acc[mf][nf], 0, 0, 0);
        acc[mf][nf] = __builtin_amdgcn_mfma_f32_16x16x32_bf16(ah[mf], bh[nf], acc[mf][nf], 0, 0, 0);
      }
  }

  // rowmax over this block's 64 columns, per row (16-lane group reduce)
#pragma unroll
  for (int mf = 0; mf < 4; mf++)
#pragma unroll
    for (int j = 0; j < 4; j++) {
      float m = fmaxf(fmaxf(acc[mf][0][j], acc[mf][1][j]),
                      fmaxf(acc[mf][2][j], acc[mf][3][j]));
#pragma unroll
      for (int mk = 1; mk <= 8; mk <<= 1) m = fmaxf(m, __shfl_xor(m, mk));
      if ((l & 15) == 0) {
        int row = w * 64 + mf * 16 + (l >> 4) * 4 + j;
        rowmax[(size_t)row * 4096 + cb] = bf16_floor(m);
      }
    }

  // epilogue: LDS transpose (reuse Bf) -> 16B/lane coalesced stores
  float* tr2 = ((float*)&Bf[0][0]) + w * (16 * 68);
#pragma unroll
  for (int mf = 0; mf < 4; mf++) {
    __syncthreads();
#pragma unroll
    for (int nf = 0; nf < 4; nf++)
#pragma unroll
      for (int j = 0; j < 4; j++)
        tr2[((l >> 4) * 4 + j) * 68 + nf * 16 + (l & 15)] = acc[mf][nf][j];
    __syncthreads();
#pragma unroll
    for (int it = 0; it < 4; it++) {
      float4 vv = *(float4*)&tr2[(it * 4 + (l >> 4)) * 68 + 4 * (l & 15)];
      size_t row = (size_t)(w * 64 + mf * 16 + it * 4 + (l >> 4));
      *(float4*)&scores[row * MEM_N + slot0 + 4 * (l & 15)] = vv;
    }
  }
}

// ---- per-row cutoff = exact KSEL-th largest of 4096 bf16 block-maxima ----
__global__ __launch_bounds__(256) void k_cut(
    const u16* __restrict__ rowmax, float* __restrict__ cut_row) {
  __shared__ int h[256];
  __shared__ int Bsh, Lsh;
  const int r = blockIdx.x, t = threadIdx.x;
  const u16* rm = rowmax + (size_t)r * 4096;
  uint4 a0 = *(const uint4*)(rm + t * 16);
  uint4 a1 = *(const uint4*)(rm + t * 16 + 8);
  u16 f[16];
  unsigned aw[8] = {a0.x, a0.y, a0.z, a0.w, a1.x, a1.y, a1.z, a1.w};
#pragma unroll
  for (int i = 0; i < 8; i++) {
    f[2 * i] = flip16((u16)(aw[i] & 0xFFFFu));
    f[2 * i + 1] = flip16((u16)(aw[i] >> 16));
  }
  h[t] = 0;
  __syncthreads();
#pragma unroll
  for (int i = 0; i < 16; i++) atomicAdd(&h[f[i] >> 8], 1);
  __syncthreads();
  for (int off = 1; off < 256; off <<= 1) {
    int v = (t + off < 256) ? h[t + off] : 0;
    __syncthreads();
    h[t] += v;
    __syncthreads();
  }
  if (h[t] >= KSEL && (t == 255 || h[t + 1] < KSEL)) Bsh = t;
  __syncthreads();
  const int B = Bsh;
  const int above = (B == 255) ? 0 : h[B + 1];
  __syncthreads();
  h[t] = 0;
  __syncthreads();
#pragma unroll
  for (int i = 0; i < 16; i++)
    if ((f[i] >> 8) == B) atomicAdd(&h[f[i] & 255], 1);
  __syncthreads();
  for (int off = 1; off < 256; off <<= 1) {
    int v = (t + off < 256) ? h[t + off] : 0;
    __syncthreads();
    h[t] += v;
    __syncthreads();
  }
  if (above + h[t] >= KSEL && (t == 255 || above + h[t + 1] < KSEL)) Lsh = t;
  __syncthreads();
  if (t == 0) {
    u16 fs = (u16)((B << 8) | Lsh);
    cut_row[r] = bf16_f32(unflip16(fs));
  }
}

// ---------------- sort helpers ----------------
__device__ void bitonic_desc(u64* a, int N, int t) {
  for (int k = 2; k <= N; k <<= 1) {
    for (int j = k >> 1; j > 0; j >>= 1) {
      for (int i = t; i < N; i += 256) {
        int p = i ^ j;
        if (p > i) {
          u64 xv = a[i], yv = a[p];
          bool up = ((i & k) == 0);
          if (up ? (xv < yv) : (xv > yv)) { a[i] = yv; a[p] = xv; }
        }
      }
      __syncthreads();
    }
  }
}
__device__ void bitonic_desc_resume(u64* a, int N, int k0, int t) {
  for (int k = k0; k <= N; k <<= 1) {
    for (int j = k >> 1; j > 0; j >>= 1) {
      for (int i = t; i < N; i += 256) {
        int p = i ^ j;
        if (p > i) {
          u64 xv = a[i], yv = a[p];
          bool up = ((i & k) == 0);
          if (up ? (xv < yv) : (xv > yv)) { a[i] = yv; a[p] = xv; }
        }
      }
      __syncthreads();
    }
  }
}
__device__ void trimN(u64* cand, int* cnt, u64* cutoff, int t, int cap) {
  int n = *cnt;
  for (int i = t; i < cap; i += 256)
    if (i >= n) cand[i] = 0ULL;
  __syncthreads();
  bitonic_desc(cand, cap, t);
  if (t == 0) { *cnt = 256; *cutoff = cand[255]; }
}

// ---- sweep: filtered top-k candidate collection (LDS-compacted) + keys copy ----
__global__ __launch_bounds__(256) void k_sweep(
    const float* __restrict__ scores, const float* __restrict__ cut_row,
    const float* __restrict__ keys, u64* __restrict__ cand_row,
    int* __restrict__ row_cnt, float* __restrict__ keys_out) {
  __shared__ u64 lbuf[2048];
  __shared__ int lcnt, gbase;
  const int seg = blockIdx.x, r = blockIdx.y, t = threadIdx.x;
  if (t == 0) lcnt = 0;
  __syncthreads();
  const float cutval = cut_row[r];
  const float* p = scores + (size_t)r * MEM_N + (size_t)seg * SEG_SZ;

  // phase A: filtered sweep, 16 float4 in flight, LDS compaction
  for (int base = 0; base < SEG_SZ; base += 16384) {
    float4 v[16];
#pragma unroll
    for (int u = 0; u < 16; u++) v[u] = *(const float4*)(p + base + u * 1024 + t * 4);
#pragma unroll
    for (int u = 0; u < 16; u++) {
      float vv[4] = {v[u].x, v[u].y, v[u].z, v[u].w};
      int c0 = seg * SEG_SZ + base + u * 1024 + t * 4;
#pragma unroll
      for (int e = 0; e < 4; e++) {
        if (vv[e] >= cutval) {
          u64 key = (((u64)flip32(vv[e])) << 32) | (unsigned)(~(unsigned)(c0 + e));
          int pz = atomicAdd(&lcnt, 1);
          if (pz < 2048) lbuf[pz] = key;
        }
      }
    }
  }
  __syncthreads();
  int n = lcnt < 2048 ? lcnt : 2048;
  if (t == 0) gbase = atomicAdd(&row_cnt[r], n);
  __syncthreads();
  const int gb = gbase;
  u64* crow = cand_row + (size_t)r * ROWCAP;
  for (int i = t; i < n; i += 256) {
    int gp = gb + i;
    if (gp < ROWCAP) crow[gp] = lbuf[i];
  }

  // phase B: keys copy into the exact region this block just read.
  const long long b = (long long)r * MEM_N + (long long)seg * SEG_SZ - 1;
  for (int i = t; i < 8192; i += 256) {
    long long k4 = b + 4LL * i;
    if (k4 < 0) continue;  // only block (0,0) i=0
    float s = keys[k4];
    float4 v = *(const float4*)(keys + k4 + 1);
    float4 o;
    o.x = s; o.y = v.x; o.z = v.y; o.w = v.z;
    *(float4*)(keys_out + k4) = o;
  }
  if (r == 0 && seg == 0 && t == 0) {
    keys_out[0] = keys[0]; keys_out[1] = keys[1]; keys_out[2] = keys[2];
  }
}

// ---------------- top-k stage 2: sort + softmax + loss + yhat ----------------
__global__ __launch_bounds__(256) void k_topk2(
    const u64* __restrict__ cand_row, const int* __restrict__ row_cnt,
    const int* __restrict__ values, const int* __restrict__ yv,
    float* __restrict__ out, float* __restrict__ loss_arr,
    int* __restrict__ corr, int* __restrict__ yidx) {
  __shared__ u64 buf[ROWCAP];
  __shared__ float red[256];
  const int r = blockIdx.x, t = threadIdx.x;
  int cnt = row_cnt[r];
  cnt = cnt < ROWCAP ? cnt : ROWCAP;
  int S = 256;
  while (S < cnt) S <<= 1;
  const u64* src = cand_row + (size_t)r * ROWCAP;
  for (int i = t; i < S; i += 256) buf[i] = (i < cnt) ? src[i] : 0ULL;
  __syncthreads();
  bitonic_desc(buf, S, t);

  u64 mykey = buf[t];
  int midx = mykey ? (int)(~(unsigned)(mykey & 0xFFFFFFFFull)) : 0;
  float msc = unflip32((unsigned)(mykey >> 32));
  int yr = yv[r];
  float mask = (values[midx] == yr) ? 1.0f : 0.0f;
  float mtop = unflip32((unsigned)(buf[0] >> 32));

  float e = expf(msc - mtop);  // TEMP == 1.0
  red[t] = e; __syncthreads();
  for (int s = 128; s > 0; s >>= 1) { if (t < s) red[t] += red[t + s]; __syncthreads(); }
  float denom = red[0]; __syncthreads();
  out[256 + r * 256 + t] = e / denom;

  red[t] = msc * mask; __syncthreads();
  for (int s = 128; s > 0; s >>= 1) { if (t < s) red[t] = fmaxf(red[t], red[t + s]); __syncthreads(); }
  float posr = red[0]; __syncthreads();

  red[t] = msc * (1.0f - mask); __syncthreads();
  for (int s = 128; s > 0; s >>= 1) { if (t < s) red[t] = fmaxf(red[t], red[t + s]); __syncthreads(); }
  float negr = red[0]; __syncthreads();

  red[t] = mask; __syncthreads();
  for (int s = 128; s > 0; s >>= 1) { if (t < s) red[t] += red[t + s]; __syncthreads(); }
  float hp = (red[0] > 0.0f) ? 1.0f : 0.0f;

  if (t == 0) {
    float pos = posr * hp;
    loss_arr[r] = fmaxf(negr - pos + 0.1f, 0.0f);
    int i0 = (int)(~(unsigned)(buf[0] & 0xFFFFFFFFull));
    out[r] = (float)values[i0];
    yidx[r] = i0;
    corr[r] = (values[i0] == yr) ? 1 : 0;
  }
}

// ---------------- age/values init ----------------
__global__ __launch_bounds__(256) void k_age(
    const float* __restrict__ age, const int* __restrict__ values,
    float* __restrict__ age_out, float* __restrict__ vals_out) {
  int i = blockIdx.x * 256 + threadIdx.x;
  age_out[i] = age[i] + 1.0f;
  vals_out[i] = (float)values[i];
}

__global__ void k_reset(const int* __restrict__ corr, const int* __restrict__ yidx,
                        float* __restrict__ age_out, const float* __restrict__ keys,
                        float* __restrict__ keys_out) {
  int t = threadIdx.x;
  if (corr[t]) age_out[yidx[t]] = 0.0f;
  if (t == 255) {
    const long long N = (long long)MEM_N * DIM;
    keys_out[N - 1] = keys[N - 1];  // only element k_sweep's copy doesn't cover
  }
}

// ---------------- oldest = top-256 of age_noisy ----------------
__global__ __launch_bounds__(256) void k_oldA(
    const float* __restrict__ age_out, const float* __restrict__ un,
    u64* __restrict__ cand_o) {
  __shared__ u64 cand[OCAP];
  __shared__ int cnt;
  __shared__ u64 cutoff;
  __shared__ u64 redu[256];
  const int t = threadIdx.x;
  const int base = blockIdx.x * 16384;
  u64 mk = 0ULL;
  for (int u = 0; u < 64; u++) {
    int g = base + u * 256 + t;
    float v = age_out[g] + (2.0f * un[g] - 1.0f) * 8.0f;
    u64 k = (((u64)flip32(v)) << 32) | (unsigned)(~(unsigned)g);
    mk = k > mk ? k : mk;
  }
  redu[t] = mk;
  __syncthreads();
  for (int s = 128; s > 0; s >>= 1) {
    if (t < s) redu[t] = (redu[t] < redu[t + s]) ? redu[t] : redu[t + s];
    __syncthreads();
  }
  if (t == 0) { cnt = 0; cutoff = redu[0] - 1ULL; }
  __syncthreads();
  for (int cb = 0; cb < 16384; cb += 2048) {
    u64 cut = cutoff;
#pragma unroll
    for (int u = 0; u < 8; u++) {
      int g = base + cb + u * 256 + t;
      float v = age_out[g] + (2.0f * un[g] - 1.0f) * 8.0f;
      u64 k = (((u64)flip32(v)) << 32) | (unsigned)(~(unsigned)g);
      if (k > cut) {
        int pz = atomicAdd(&cnt, 1);
        if (pz < OCAP) cand[pz] = k;
      }
    }
    __syncthreads();
    if (cnt > 2048) trimN(cand, &cnt, &cutoff, t, OCAP);
    __syncthreads();
  }
  int n = cnt < OCAP ? cnt : OCAP;
  int S = 256;
  while (S < n) S <<= 1;
  for (int i = t; i < S; i += 256)
    if (i >= n) cand[i] = 0ULL;
  __syncthreads();
  bitonic_desc(cand, S, t);
  cand_o[blockIdx.x * 256 + t] = cand[t];
}

__global__ __launch_bounds__(256) void k_oldB(
    const u64* __restrict__ cand_o, const int* __restrict__ corr,
    const float* __restrict__ loss_arr, int* __restrict__ dest,
    float* __restrict__ out_loss) {
  __shared__ u64 cand[4096];
  __shared__ int olds[256];
  __shared__ int pre[256];
  __shared__ float red[256];
  const int t = threadIdx.x;
  for (int i = t; i < 4096; i += 256) {
    int j = i >> 8, jj = i & 255;
    int src = (j & 1) ? (j * 256 + 255 - jj) : i;
    cand[i] = cand_o[src];
  }
  __syncthreads();
  bitonic_desc_resume(cand, 4096, 512, t);
  olds[t] = (int)(~(unsigned)(cand[t] & 0xFFFFFFFFull));
  int inc = corr[t] ? 0 : 1;
  pre[t] = inc;
  __syncthreads();
  for (int off = 1; off < 256; off <<= 1) {
    int v = (t >= off) ? pre[t - off] : 0;
    __syncthreads();
    pre[t] += v;
    __syncthreads();
  }
  int rank = pre[t] - 1;
  dest[t] = inc ? olds[rank] : -1;
  red[t] = loss_arr[t]; __syncthreads();
  for (int s = 128; s > 0; s >>= 1) { if (t < s) red[t] += red[t + s]; __syncthreads(); }
  if (t == 0) *out_loss = red[0] * (1.0f / 256.0f);
}

// ---------------- scatter updates ----------------
__global__ __launch_bounds__(256) void k_correct(
    const int* __restrict__ corr, const int* __restrict__ yidx,
    const float* __restrict__ keys, const float* __restrict__ q,
    float* __restrict__ keys_out) {
  const int r = blockIdx.x;
  if (!corr[r]) return;
  const int t = threadIdx.x;
  __shared__ float red[256];
  int d = yidx[r];
  float v = keys[(size_t)d * DIM + t] + q[r * DIM + t];
  red[t] = v * v; __syncthreads();
  for (int s = 128; s > 0; s >>= 1) { if (t < s) red[t] += red[t + s]; __syncthreads(); }
  float nrm = fmaxf(sqrtf(red[0]), 1e-12f);
  keys_out[(size_t)d * DIM + t] = v / nrm;
}

__global__ __launch_bounds__(256) void k_incorrect(
    const int* __restrict__ dest, const float* __restrict__ q,
    const int* __restrict__ yv, float* __restrict__ keys_out,
    float* __restrict__ vals_out, float* __restrict__ age_out) {
  const int r = blockIdx.x;
  int d = dest[r];
  if (d < 0) return;
  const int t = threadIdx.x;
  keys_out[(size_t)d * DIM + t] = q[r * DIM + t];
  if (t == 0) {
    vals_out[d] = (float)yv[r];
    age_out[d] = 0.0f;
  }
}

extern "C" void kernel_launch(void* const* d_in, const int* in_sizes, int n_in,
                              void* d_out, int out_size, void* d_ws, size_t ws_size,
                              hipStream_t stream) {
  const float* x = (const float*)d_in[0];
  const int* y = (const int*)d_in[1];
  const float* W = (const float*)d_in[2];
  const float* b = (const float*)d_in[3];
  const float* keys = (const float*)d_in[4];
  const int* values = (const int*)d_in[5];
  const float* age = (const float*)d_in[6];
  const float* un = (const float*)d_in[7];
  float* out = (float*)d_out;

  char* ws = (char*)d_ws;
  float* q = (float*)ws;                             // 256 KB
  u16* ap_hi = (u16*)(ws + 262144);                  // 128 KB
  u16* ap_lo = (u16*)(ws + 393216);                  // 128 KB
  float* loss_arr = (float*)(ws + 524288);           // 1 KB
  int* corr = (int*)(ws + 525312);                   // 1 KB
  int* yidx = (int*)(ws + 526336);                   // 1 KB
  u64* cand_o = (u64*)(ws + 527360);                 // 32 KB
  int* dest = (int*)(ws + 560128);                   // 1 KB
  int* row_cnt = (int*)(ws + 561152);                // 1 KB
  float* cut_row = (float*)(ws + 562176);            // 1 KB
  u64* cand_row = (u64*)(ws + 1048576);              // 4 MB (256 x ROWCAP)

  // d_out layout (floats): yhat[256] | softmax[65536] | loss[1] | keys[67108864]
  //                        | values[262144] | age[262144]
  const size_t LOSS_OFF = 65792, KEYS_OFF = 65793, VALS_OFF = 67174657,
               AGE_OFF = 67436801;
  float* scores = out + 65792;          // 256 MB scratch over loss+keys region
  u16* rowmax = (u16*)(out + 67174656); // 2 MB scratch over last-key+values+age
  float* keys_out = out + KEYS_OFF;
  float* vals_out = out + VALS_OFF;
  float* age_out = out + AGE_OFF;

  k_query<<<dim3(256), dim3(256), 0, stream>>>(x, W, b, q, ap_hi, ap_lo, row_cnt);
  k_gemm<<<dim3(4096), dim3(256), 0, stream>>>(ap_hi, ap_lo, keys, scores, rowmax);
  k_cut<<<dim3(256), dim3(256), 0, stream>>>(rowmax, cut_row);
  k_sweep<<<dim3(NSEG, 256), dim3(256), 0, stream>>>(scores, cut_row, keys, cand_row, row_cnt, keys_out);
  k_topk2<<<dim3(256), dim3(256), 0, stream>>>(cand_row, row_cnt, values, y, out, loss_arr, corr, yidx);
  k_age<<<dim3(1024), dim3(256), 0, stream>>>(age, values, age_out, vals_out);
  k_reset<<<dim3(1), dim3(256), 0, stream>>>(corr, yidx, age_out, keys, keys_out);
  k_oldA<<<dim3(16), dim3(256), 0, stream>>>(age_out, un, cand_o);
  k_oldB<<<dim3(1), dim3(256), 0, stream>>>(cand_o, corr, loss_arr, dest, out + LOSS_OFF);
  k_correct<<<dim3(256), dim3(256), 0, stream>>>(corr, yidx, keys, q, keys_out);
  k_incorrect<<<dim3(256), dim3(256), 0, stream>>>(dest, q, y, keys_out, vals_out, age_out);
}